// Round 6
// baseline (656.284 us; speedup 1.0000x reference)
//
#include <hip/hip_runtime.h>

#define NN 50000
#define NE 800000
#define INC 32
#define HH 64
#define H2 128
#define OC 16
#define ON 17
#define NL 4
#define MEPS 1e-7f
#define LNE 1e-5f
#define SCAN_BLOCKS 196   /* ceil(50000/256) */

typedef __attribute__((ext_vector_type(8))) short bf16x8;
typedef __attribute__((ext_vector_type(4))) float f32x4;

// ---------- ordered-uint encoding for float atomic max ----------
__device__ __forceinline__ unsigned fenc(float x) {
    unsigned u = __float_as_uint(x);
    return (u & 0x80000000u) ? ~u : (u | 0x80000000u);
}
__device__ __forceinline__ float fdec(unsigned u) {
    return (u & 0x80000000u) ? __uint_as_float(u & 0x7fffffffu)
                             : __uint_as_float(~u);
}
// ---------- bf16 helpers (RNE) ----------
__device__ __forceinline__ unsigned short f2b(float x) {
    unsigned b = __float_as_uint(x);
    b += 0x7FFFu + ((b >> 16) & 1u);
    return (unsigned short)(b >> 16);
}
__device__ __forceinline__ float b2f(unsigned short u) {
    return __uint_as_float(((unsigned)u) << 16);
}

// ---------- CSR build ----------
__global__ __launch_bounds__(256) void k_hist2(const int* __restrict__ dst, int* __restrict__ counts,
                                               int* __restrict__ rank) {
    int e = blockIdx.x * 256 + threadIdx.x;
    if (e < NE) rank[e] = atomicAdd(&counts[dst[e]], 1);
}

__global__ __launch_bounds__(256) void k_scan1(const int* __restrict__ counts,
                                               int* __restrict__ incl, int* __restrict__ bsums) {
    __shared__ int s[256];
    int t = threadIdx.x;
    int i = blockIdx.x * 256 + t;
    int v = (i < NN) ? counts[i] : 0;
    s[t] = v;
    __syncthreads();
    for (int off = 1; off < 256; off <<= 1) {
        int x = (t >= off) ? s[t - off] : 0;
        __syncthreads();
        s[t] += x;
        __syncthreads();
    }
    if (i < NN) incl[i] = s[t];
    if (t == 255) bsums[blockIdx.x] = s[255];
}

__global__ __launch_bounds__(256) void k_scan2(int* __restrict__ bsums) {
    __shared__ int s[256];
    int t = threadIdx.x;
    int v = (t < SCAN_BLOCKS) ? bsums[t] : 0;
    s[t] = v;
    __syncthreads();
    for (int off = 1; off < 256; off <<= 1) {
        int x = (t >= off) ? s[t - off] : 0;
        __syncthreads();
        s[t] += x;
        __syncthreads();
    }
    if (t < SCAN_BLOCKS) bsums[t] = s[t] - v;  // exclusive
}

__global__ __launch_bounds__(256) void k_scan3(const int* __restrict__ counts,
                                               int* __restrict__ rowst, const int* __restrict__ bsums) {
    int i = blockIdx.x * 256 + threadIdx.x;
    if (i < NN) rowst[i] = rowst[i] - counts[i] + bsums[blockIdx.x];
}

__global__ __launch_bounds__(256) void k_scatter2(const int* __restrict__ src, const int* __restrict__ dst,
                                                  const int* __restrict__ rank, const int* __restrict__ rowst,
                                                  int* __restrict__ ssrc) {
    int e = blockIdx.x * 256 + threadIdx.x;
    if (e < NE) ssrc[rowst[dst[e]] + rank[e]] = src[e];
}

// ---------- weight prep (one-time): transpose + bf16 hi/lo split ----------
// w1t[c][k] (c<128,k<64), w2t[c][k] (c<64,k<128); head weights into padded [48][64]
// combined tile (j<17 n-head, j in [17,33) g-head, rest zero) + combined bias bc[48].
__global__ __launch_bounds__(256) void k_wprep(const float* __restrict__ W1, const float* __restrict__ W2,
                                               const float* __restrict__ nW, const float* __restrict__ gW,
                                               const float* __restrict__ nbp, const float* __restrict__ gb,
                                               unsigned short* __restrict__ w1h, unsigned short* __restrict__ w1l,
                                               unsigned short* __restrict__ w2h, unsigned short* __restrict__ w2l,
                                               unsigned short* __restrict__ whh, unsigned short* __restrict__ whl,
                                               float* __restrict__ bc) {
    int i = blockIdx.x * 256 + threadIdx.x;
    if (i < 48 * 64) {
        int j = i >> 6, k = i & 63;
        float v = 0.f;
        if (j < ON) v = nW[k * ON + j];
        else if (j < 33) v = gW[k * OC + (j - ON)];
        unsigned short hi = f2b(v);
        whh[i] = hi;
        whl[i] = f2b(v - b2f(hi));
    }
    if (i < 48) bc[i] = (i < ON) ? nbp[i] : ((i < 33) ? gb[i - ON] : 0.f);
    if (i >= NL * H2 * HH) return;
    int l = i / (H2 * HH), r = i % (H2 * HH);
    {
        int c = r / HH, k = r % HH;
        float v = W1[(size_t)l * HH * H2 + (size_t)k * H2 + c];
        unsigned short hi = f2b(v);
        w1h[i] = hi;
        w1l[i] = f2b(v - b2f(hi));
    }
    {
        int c = r / H2, k = r % H2;
        float v = W2[(size_t)l * H2 * HH + (size_t)k * HH + c];
        unsigned short hi = f2b(v);
        w2h[i] = hi;
        w2l[i] = f2b(v - b2f(hi));
    }
}

// ---------- node encoder: h = x @ W + b  ([N,32]@[32,64]), also bf16 shadow ----------
__global__ __launch_bounds__(256) void k_encoder(const float* __restrict__ x, const float* __restrict__ W,
                                                 const float* __restrict__ b, float* __restrict__ h,
                                                 unsigned short* __restrict__ hbf) {
    __shared__ float Ws[INC * HH];
    __shared__ float bs[HH];
    int tid = threadIdx.x;
    for (int i = tid; i < INC * HH; i += 256) Ws[i] = W[i];
    if (tid < HH) bs[tid] = b[tid];
    __syncthreads();
    int wid = tid >> 6, lane = tid & 63;
    int n = blockIdx.x * 4 + wid;
    if (n >= NN) return;
    float v = (lane < INC) ? x[(size_t)n * INC + lane] : 0.f;
    float acc = bs[lane];
    #pragma unroll
    for (int k = 0; k < INC; ++k)
        acc += __shfl(v, k) * Ws[k * HH + lane];
    h[(size_t)n * HH + lane] = acc;
    hbf[(size_t)n * HH + lane] = f2b(acc);
}

// ---------- per-dst softmax aggregation, dual-row gathers ----------
__global__ __launch_bounds__(256) void k_agg(const float* __restrict__ y,
                                             const unsigned short* __restrict__ ybf,
                                             const int* __restrict__ rowst,
                                             const int* __restrict__ counts, const int* __restrict__ ssrc,
                                             const float* __restrict__ tp,
                                             unsigned short* __restrict__ agh,
                                             unsigned short* __restrict__ agl) {
    int tid = threadIdx.x;
    int wid = tid >> 6, lane = tid & 63;
    int n = blockIdx.x * 4 + wid;
    if (n >= NN) return;
    float tval = *tp;
    int start = rowst[n];
    int deg = counts[n];
    float Sa = 0.f, Sma = 0.f;
    if (deg > 0 && deg <= 64) {
        int myidx = (lane < deg) ? ssrc[start + lane] : 0;
        int half = lane >> 5;      // edge parity this lane handles
        int col = lane & 31;       // channel-pair index
        float Sa0 = 0.f, Sa1 = 0.f, Sm0 = 0.f, Sm1 = 0.f;
        for (int base = 0; base < deg; base += 16) {
            float c0[8], c1[8];
            int eidx[8];
            #pragma unroll
            for (int i = 0; i < 8; ++i) {
                int e = base + 2 * i + half;
                eidx[i] = e;
                int es = (e < deg) ? e : (deg - 1);
                int s = __shfl(myidx, es);
                unsigned v = *(const unsigned*)(ybf + (size_t)s * HH + col * 2);
                c0[i] = b2f((unsigned short)(v & 0xffffu));
                c1[i] = b2f((unsigned short)(v >> 16));
            }
            #pragma unroll
            for (int i = 0; i < 8; ++i) {
                bool ok = eidx[i] < deg;
                float m0 = fmaxf(c0[i], 0.f) + MEPS;
                float m1 = fmaxf(c1[i], 0.f) + MEPS;
                float a0 = ok ? __expf(tval * m0) : 0.f;
                float a1 = ok ? __expf(tval * m1) : 0.f;
                Sa0 += a0; Sm0 += m0 * a0;
                Sa1 += a1; Sm1 += m1 * a1;
            }
        }
        Sa0 += __shfl_xor(Sa0, 32); Sa1 += __shfl_xor(Sa1, 32);
        Sm0 += __shfl_xor(Sm0, 32); Sm1 += __shfl_xor(Sm1, 32);
        int srcl = lane >> 1;
        float saA = __shfl(Sa0, srcl), saB = __shfl(Sa1, srcl);
        float smA = __shfl(Sm0, srcl), smB = __shfl(Sm1, srcl);
        Sa = (lane & 1) ? saB : saA;
        Sma = (lane & 1) ? smB : smA;
    } else if (deg > 64) {
        for (int e = 0; e < deg; ++e) {
            int s = ssrc[start + e];
            float v = b2f(ybf[(size_t)s * HH + lane]);
            float m = fmaxf(v, 0.f) + MEPS;
            float a = __expf(tval * m);
            Sa += a; Sma += m * a;
        }
    }
    float agg = Sma / fmaxf(Sa, MEPS);  // deg==0 -> 0
    float av = agg + y[(size_t)n * HH + lane];
    unsigned short hi = f2b(av);
    agh[(size_t)n * HH + lane] = hi;
    agl[(size_t)n * HH + lane] = f2b(av - b2f(hi));
}

// ---------- MFMA fused MLP, swapped-operand form; zero block barriers ----------
__global__ __launch_bounds__(256) void k_mlp(
    const unsigned short* __restrict__ agh, const unsigned short* __restrict__ agl,
    const unsigned short* __restrict__ w1h, const unsigned short* __restrict__ w1l,
    const float* __restrict__ b1,
    const float* __restrict__ mlg, const float* __restrict__ mlb,
    const unsigned short* __restrict__ w2h, const unsigned short* __restrict__ w2l,
    const float* __restrict__ b2,
    const float* __restrict__ hres, float* __restrict__ hout,
    const float* __restrict__ lng1, const float* __restrict__ lnb1,
    float* __restrict__ y, unsigned short* __restrict__ ybf)
{
    __shared__ __align__(16) unsigned short Ut[4][16 * 136];  // stride 136 shorts: bank-stagger
    int tid = threadIdx.x;
    int w = tid >> 6, lane = tid & 63;
    int nl = lane & 15, g = lane >> 4;
    int node = blockIdx.x * 64 + w * 16 + nl;
    bool valid = node < NN;

    // B-frags for gemmA: ag^T tile; B[k][j]: j=lane&15=node, k=(lane>>4)*8+e
    bf16x8 bAh[2], bAl[2];
    {
        bf16x8 z = {0, 0, 0, 0, 0, 0, 0, 0};
        if (valid) {
            const unsigned short* rp = agh + (size_t)node * HH + g * 8;
            bAh[0] = *(const bf16x8*)rp;
            bAh[1] = *(const bf16x8*)(rp + 32);
            const unsigned short* rq = agl + (size_t)node * HH + g * 8;
            bAl[0] = *(const bf16x8*)rq;
            bAl[1] = *(const bf16x8*)(rq + 32);
        } else {
            bAh[0] = z; bAh[1] = z; bAl[0] = z; bAl[1] = z;
        }
    }

    // gemmA: U^T tiles (8 x 16 ucols), K=64. 3 MFMA per (t,kc)
    f32x4 accU[8];
    #pragma unroll
    for (int t = 0; t < 8; ++t) {
        int uc = t * 16 + g * 4;
        float4 bb = *(const float4*)(b1 + uc);
        f32x4 a = {bb.x, bb.y, bb.z, bb.w};
        #pragma unroll
        for (int kc = 0; kc < 2; ++kc) {
            size_t wo = (size_t)(t * 16 + nl) * 64 + kc * 32 + g * 8;
            bf16x8 ah = *(const bf16x8*)(w1h + wo);
            bf16x8 al = *(const bf16x8*)(w1l + wo);
            a = __builtin_amdgcn_mfma_f32_16x16x32_bf16(ah, bAh[kc], a, 0, 0, 0);
            a = __builtin_amdgcn_mfma_f32_16x16x32_bf16(al, bAh[kc], a, 0, 0, 0);
            a = __builtin_amdgcn_mfma_f32_16x16x32_bf16(ah, bAl[kc], a, 0, 0, 0);
        }
        accU[t] = a;
    }

    // LN(128): node = lane&15 -> reduce in-lane + across the 4 lane-groups
    float s = 0.f, sq = 0.f;
    #pragma unroll
    for (int t = 0; t < 8; ++t) {
        #pragma unroll
        for (int j = 0; j < 4; ++j) { float v = accU[t][j]; s += v; sq += v * v; }
    }
    s += __shfl_xor(s, 16); sq += __shfl_xor(sq, 16);
    s += __shfl_xor(s, 32); sq += __shfl_xor(sq, 32);
    float mu = s * (1.f / 128.f);
    float var = sq * (1.f / 128.f) - mu * mu;
    float rs = rsqrtf(fmaxf(var, 0.f) + LNE);

    // normalize + relu + pack bf16 -> Ut[node][ucol]
    #pragma unroll
    for (int t = 0; t < 8; ++t) {
        int uc = t * 16 + g * 4;
        float4 gg = *(const float4*)(mlg + uc);
        float4 bb = *(const float4*)(mlb + uc);
        ushort4 pk;
        pk.x = f2b(fmaxf((accU[t][0] - mu) * rs * gg.x + bb.x, 0.f));
        pk.y = f2b(fmaxf((accU[t][1] - mu) * rs * gg.y + bb.y, 0.f));
        pk.z = f2b(fmaxf((accU[t][2] - mu) * rs * gg.z + bb.z, 0.f));
        pk.w = f2b(fmaxf((accU[t][3] - mu) * rs * gg.w + bb.w, 0.f));
        *(ushort4*)(&Ut[w][nl * 136 + uc]) = pk;
    }
    // cross-LANE (same wave) LDS dependency: drain our wave's ds_writes
    asm volatile("s_waitcnt lgkmcnt(0)" ::: "memory");

    // B-frags for gemmB: P^T
    bf16x8 bB[4];
    #pragma unroll
    for (int kc = 0; kc < 4; ++kc)
        bB[kc] = *(const bf16x8*)(&Ut[w][nl * 136 + kc * 32 + g * 8]);

    // gemmB: O^T tiles (4 x 16 ocols), K=128. 2 MFMA per (ot,kc)
    f32x4 accO[4];
    #pragma unroll
    for (int ot = 0; ot < 4; ++ot) {
        int oc = ot * 16 + g * 4;
        float4 bb = *(const float4*)(b2 + oc);
        f32x4 a = {bb.x, bb.y, bb.z, bb.w};
        #pragma unroll
        for (int kc = 0; kc < 4; ++kc) {
            size_t wo = (size_t)(ot * 16 + nl) * 128 + kc * 32 + g * 8;
            bf16x8 ah = *(const bf16x8*)(w2h + wo);
            bf16x8 al = *(const bf16x8*)(w2l + wo);
            a = __builtin_amdgcn_mfma_f32_16x16x32_bf16(ah, bB[kc], a, 0, 0, 0);
            a = __builtin_amdgcn_mfma_f32_16x16x32_bf16(al, bB[kc], a, 0, 0, 0);
        }
        accO[ot] = a;
    }

    // epilogue: +residual, write h
    float4 oo[4];
    #pragma unroll
    for (int ot = 0; ot < 4; ++ot) {
        int oc = ot * 16 + g * 4;
        float4 o;
        o.x = accO[ot][0]; o.y = accO[ot][1]; o.z = accO[ot][2]; o.w = accO[ot][3];
        if (valid) {
            if (hres) {
                float4 hr = *(const float4*)(hres + (size_t)node * HH + oc);
                o.x += hr.x; o.y += hr.y; o.z += hr.z; o.w += hr.w;
            }
            *(float4*)(hout + (size_t)node * HH + oc) = o;
        }
        oo[ot] = o;
    }
    if (!lng1) return;   // last layer: k_outg does the final LN (uniform exit)

    // next-layer LN(64)+ReLU, all in registers
    float s2 = 0.f, sq2 = 0.f;
    #pragma unroll
    for (int ot = 0; ot < 4; ++ot) {
        s2 += oo[ot].x + oo[ot].y + oo[ot].z + oo[ot].w;
        sq2 += oo[ot].x * oo[ot].x + oo[ot].y * oo[ot].y
             + oo[ot].z * oo[ot].z + oo[ot].w * oo[ot].w;
    }
    s2 += __shfl_xor(s2, 16); sq2 += __shfl_xor(sq2, 16);
    s2 += __shfl_xor(s2, 32); sq2 += __shfl_xor(sq2, 32);
    float mu2 = s2 * (1.f / 64.f);
    float var2 = sq2 * (1.f / 64.f) - mu2 * mu2;
    float rs2 = rsqrtf(fmaxf(var2, 0.f) + LNE);
    #pragma unroll
    for (int ot = 0; ot < 4; ++ot) {
        int oc = ot * 16 + g * 4;
        float4 gg = *(const float4*)(lng1 + oc);
        float4 bb = *(const float4*)(lnb1 + oc);
        float4 v;
        v.x = fmaxf((oo[ot].x - mu2) * rs2 * gg.x + bb.x, 0.f);
        v.y = fmaxf((oo[ot].y - mu2) * rs2 * gg.y + bb.y, 0.f);
        v.z = fmaxf((oo[ot].z - mu2) * rs2 * gg.z + bb.z, 0.f);
        v.w = fmaxf((oo[ot].w - mu2) * rs2 * gg.w + bb.w, 0.f);
        if (valid) {
            *(float4*)(y + (size_t)node * HH + oc) = v;
            ushort4 p;
            p.x = f2b(v.x); p.y = f2b(v.y); p.z = f2b(v.z); p.w = f2b(v.w);
            *(ushort4*)(ybf + (size_t)node * HH + oc) = p;
        }
    }
}

// ---------- MFMA final LN + both heads; zero LDS, zero barriers ----------
// Same swapped-operand recipe as k_mlp: node = lane&15, LN lane-local, heads via
// padded [48][64] hi/lo weight tile (j<17 n-head, j in [17,33) g-head).
__global__ __launch_bounds__(256) void k_outg(const float* __restrict__ h,
                                              const float* __restrict__ lng, const float* __restrict__ lnb,
                                              const unsigned short* __restrict__ whh,
                                              const unsigned short* __restrict__ whl,
                                              const float* __restrict__ bc,
                                              float* __restrict__ dout, unsigned* __restrict__ genc) {
    int tid = threadIdx.x;
    int w = tid >> 6, lane = tid & 63;
    int nl = lane & 15, g = lane >> 4;
    int node = blockIdx.x * 64 + w * 16 + nl;
    bool valid = node < NN;

    // load h chunks: k = kc*32 + g*8 + e
    float hv[16];
    if (valid) {
        const float* hp = h + (size_t)node * HH;
        float4 a0 = *(const float4*)(hp + g * 8);
        float4 a1 = *(const float4*)(hp + g * 8 + 4);
        float4 a2 = *(const float4*)(hp + 32 + g * 8);
        float4 a3 = *(const float4*)(hp + 32 + g * 8 + 4);
        hv[0] = a0.x; hv[1] = a0.y; hv[2] = a0.z; hv[3] = a0.w;
        hv[4] = a1.x; hv[5] = a1.y; hv[6] = a1.z; hv[7] = a1.w;
        hv[8] = a2.x; hv[9] = a2.y; hv[10] = a2.z; hv[11] = a2.w;
        hv[12] = a3.x; hv[13] = a3.y; hv[14] = a3.z; hv[15] = a3.w;
    } else {
        #pragma unroll
        for (int i = 0; i < 16; ++i) hv[i] = 0.f;
    }

    // LN(64) stats: in-lane + combine the 4 g-groups (nl preserved)
    float s = 0.f, sq = 0.f;
    #pragma unroll
    for (int i = 0; i < 16; ++i) { s += hv[i]; sq += hv[i] * hv[i]; }
    s += __shfl_xor(s, 16); sq += __shfl_xor(sq, 16);
    s += __shfl_xor(s, 32); sq += __shfl_xor(sq, 32);
    float mu = s * (1.f / 64.f);
    float var = sq * (1.f / 64.f) - mu * mu;
    float rs = rsqrtf(fmaxf(var, 0.f) + LNE);

    // normalize + relu, pack bf16 hi/lo B-frags
    union { bf16x8 v; unsigned short u[8]; } Bh[2], Bl[2];
    #pragma unroll
    for (int kc = 0; kc < 2; ++kc) {
        int cb = kc * 32 + g * 8;
        float4 g0 = *(const float4*)(lng + cb);
        float4 g1 = *(const float4*)(lng + cb + 4);
        float4 b0 = *(const float4*)(lnb + cb);
        float4 b1v = *(const float4*)(lnb + cb + 4);
        float gv[8] = {g0.x, g0.y, g0.z, g0.w, g1.x, g1.y, g1.z, g1.w};
        float bv[8] = {b0.x, b0.y, b0.z, b0.w, b1v.x, b1v.y, b1v.z, b1v.w};
        #pragma unroll
        for (int e = 0; e < 8; ++e) {
            float v = fmaxf((hv[kc * 8 + e] - mu) * rs * gv[e] + bv[e], 0.f);
            unsigned short hi = f2b(v);
            Bh[kc].u[e] = hi;
            Bl[kc].u[e] = f2b(v - b2f(hi));
        }
    }

    // heads: 3 output tiles (j = t*16 + g*4 + reg), K=64, 3 MFMA per (t,kc)
    f32x4 acc[3];
    #pragma unroll
    for (int t = 0; t < 3; ++t) {
        int j0 = t * 16 + g * 4;
        float4 bb = *(const float4*)(bc + j0);
        f32x4 a = {bb.x, bb.y, bb.z, bb.w};
        #pragma unroll
        for (int kc = 0; kc < 2; ++kc) {
            size_t wo = (size_t)(t * 16 + nl) * 64 + kc * 32 + g * 8;
            bf16x8 ah = *(const bf16x8*)(whh + wo);
            bf16x8 al = *(const bf16x8*)(whl + wo);
            a = __builtin_amdgcn_mfma_f32_16x16x32_bf16(ah, Bh[kc].v, a, 0, 0, 0);
            a = __builtin_amdgcn_mfma_f32_16x16x32_bf16(al, Bh[kc].v, a, 0, 0, 0);
            a = __builtin_amdgcn_mfma_f32_16x16x32_bf16(ah, Bl[kc].v, a, 0, 0, 0);
        }
        acc[t] = a;
    }

    // scatter: n-head direct stores; g-head butterfly-max over the 16 node-lanes
    #pragma unroll
    for (int t = 0; t < 3; ++t) {
        #pragma unroll
        for (int reg = 0; reg < 4; ++reg) {
            int j = t * 16 + g * 4 + reg;   // uniform within a g-group
            float val = acc[t][reg];
            if (j < ON) {
                if (valid) dout[OC + (size_t)node * ON + j] = val;
            } else if (j < 33) {
                float gv = valid ? val : -INFINITY;
                #pragma unroll
                for (int m = 1; m < 16; m <<= 1) gv = fmaxf(gv, __shfl_xor(gv, m));
                if (nl == 0) atomicMax(&genc[j - ON], fenc(gv));
            }
        }
    }
}

__global__ void k_gdec(const unsigned* __restrict__ genc, float* __restrict__ dout) {
    int t = threadIdx.x;
    if (t < OC) dout[t] = fdec(genc[t]);
}

// ---------- launch ----------
extern "C" void kernel_launch(void* const* d_in, const int* in_sizes, int n_in,
                              void* d_out, int out_size, void* d_ws, size_t ws_size,
                              hipStream_t stream) {
    const float* x     = (const float*)d_in[0];
    const float* nodeW = (const float*)d_in[1];
    const float* nodeB = (const float*)d_in[2];
    const float* W1    = (const float*)d_in[3];
    const float* b1    = (const float*)d_in[4];
    const float* mlg   = (const float*)d_in[5];
    const float* mlb   = (const float*)d_in[6];
    const float* W2    = (const float*)d_in[7];
    const float* b2    = (const float*)d_in[8];
    const float* tt    = (const float*)d_in[9];
    const float* lng   = (const float*)d_in[10];
    const float* lnb   = (const float*)d_in[11];
    const int*   ei    = (const int*)d_in[12];
    const float* gW    = (const float*)d_in[13];
    const float* gb    = (const float*)d_in[14];
    const float* nW    = (const float*)d_in[15];
    const float* nbp   = (const float*)d_in[16];
    float* out = (float*)d_out;

    char* ws = (char*)d_ws;
    size_t off = 0;
    auto alloc = [&](size_t bytes) -> void* {
        void* p = ws + off;
        off = (off + bytes + 255) & ~(size_t)255;
        return p;
    };
    int* counts    = (int*)alloc((size_t)NN * 4);
    unsigned* genc = (unsigned*)alloc(64);
    size_t zero_end = off;
    int* bsums = (int*)alloc(1024);
    int* rowst = (int*)alloc((size_t)NN * 4);
    int* ssrc  = (int*)alloc((size_t)NE * 4);
    float* h   = (float*)alloc((size_t)NN * HH * 4);
    float* y   = (float*)alloc((size_t)NN * HH * 4);
    unsigned short* agh = (unsigned short*)alloc((size_t)NN * HH * 2);
    unsigned short* agl = (unsigned short*)alloc((size_t)NN * HH * 2);
    unsigned short* ybf = (unsigned short*)alloc((size_t)NN * HH * 2);
    unsigned short* w1h = (unsigned short*)alloc((size_t)NL * H2 * HH * 2);
    unsigned short* w1l = (unsigned short*)alloc((size_t)NL * H2 * HH * 2);
    unsigned short* w2h = (unsigned short*)alloc((size_t)NL * H2 * HH * 2);
    unsigned short* w2l = (unsigned short*)alloc((size_t)NL * H2 * HH * 2);
    unsigned short* whh = (unsigned short*)alloc((size_t)48 * 64 * 2);
    unsigned short* whl = (unsigned short*)alloc((size_t)48 * 64 * 2);
    float* bc = (float*)alloc(48 * 4);
    int* rank = (int*)agh;   // alias: rank only lives during CSR build (3.2MB <= 6.4MB)

    const int* esrc = ei;
    const int* edst = ei + NE;

    hipMemsetAsync(d_ws, 0, zero_end, stream);

    k_wprep<<<(NL * H2 * HH + 255) / 256, 256, 0, stream>>>(W1, W2, nW, gW, nbp, gb,
                                                            w1h, w1l, w2h, w2l, whh, whl, bc);
    k_hist2<<<(NE + 255) / 256, 256, 0, stream>>>(edst, counts, rank);
    k_scan1<<<SCAN_BLOCKS, 256, 0, stream>>>(counts, rowst, bsums);
    k_scan2<<<1, 256, 0, stream>>>(bsums);
    k_scan3<<<SCAN_BLOCKS, 256, 0, stream>>>(counts, rowst, bsums);
    k_scatter2<<<(NE + 255) / 256, 256, 0, stream>>>(esrc, edst, rank, rowst, ssrc);
    k_encoder<<<(NN + 3) / 4, 256, 0, stream>>>(x, nodeW, nodeB, h, ybf);

    for (int l = 0; l < NL; ++l) {
        const float* yin = (l == 0) ? h : y;
        k_agg<<<(NN + 3) / 4, 256, 0, stream>>>(yin, ybf, rowst, counts, ssrc, tt + l, agh, agl);
        const float* ln1g = (l < NL - 1) ? (lng + (size_t)(l + 1) * HH) : nullptr;
        const float* ln1b = (l < NL - 1) ? (lnb + (size_t)(l + 1) * HH) : nullptr;
        k_mlp<<<(NN + 63) / 64, 256, 0, stream>>>(agh, agl,
                                                  w1h + (size_t)l * H2 * HH, w1l + (size_t)l * H2 * HH,
                                                  b1 + (size_t)l * H2,
                                                  mlg + (size_t)l * H2, mlb + (size_t)l * H2,
                                                  w2h + (size_t)l * H2 * HH, w2l + (size_t)l * H2 * HH,
                                                  b2 + (size_t)l * HH,
                                                  (l == 0) ? (const float*)nullptr : h, h,
                                                  ln1g, ln1b, y, ybf);
    }
    k_outg<<<(NN + 63) / 64, 256, 0, stream>>>(h, lng, lnb, whh, whl, bc, out, genc);
    k_gdec<<<1, 64, 0, stream>>>(genc, out);
}

// Round 7
// 508.123 us; speedup vs baseline: 1.2916x; 1.2916x over previous
//
#include <hip/hip_runtime.h>

#define NN 50000
#define NE 800000
#define INC 32
#define HH 64
#define H2 128
#define OC 16
#define ON 17
#define NL 4
#define MEPS 1e-7f
#define LNE 1e-5f
#define SCAN_BLOCKS 196   /* ceil(50000/256) */
#define NOB ((NN + 63) / 64)   /* k_outg blocks = 782 */

typedef __attribute__((ext_vector_type(8))) short bf16x8;
typedef __attribute__((ext_vector_type(4))) float f32x4;

// ---------- bf16 helpers (RNE) ----------
__device__ __forceinline__ unsigned short f2b(float x) {
    unsigned b = __float_as_uint(x);
    b += 0x7FFFu + ((b >> 16) & 1u);
    return (unsigned short)(b >> 16);
}
__device__ __forceinline__ float b2f(unsigned short u) {
    return __uint_as_float(((unsigned)u) << 16);
}

// ---------- CSR build ----------
__global__ __launch_bounds__(256) void k_hist2(const int* __restrict__ dst, int* __restrict__ counts,
                                               int* __restrict__ rank) {
    int e = blockIdx.x * 256 + threadIdx.x;
    if (e < NE) rank[e] = atomicAdd(&counts[dst[e]], 1);
}

__global__ __launch_bounds__(256) void k_scan1(const int* __restrict__ counts,
                                               int* __restrict__ incl, int* __restrict__ bsums) {
    __shared__ int s[256];
    int t = threadIdx.x;
    int i = blockIdx.x * 256 + t;
    int v = (i < NN) ? counts[i] : 0;
    s[t] = v;
    __syncthreads();
    for (int off = 1; off < 256; off <<= 1) {
        int x = (t >= off) ? s[t - off] : 0;
        __syncthreads();
        s[t] += x;
        __syncthreads();
    }
    if (i < NN) incl[i] = s[t];
    if (t == 255) bsums[blockIdx.x] = s[255];
}

__global__ __launch_bounds__(256) void k_scan2(int* __restrict__ bsums) {
    __shared__ int s[256];
    int t = threadIdx.x;
    int v = (t < SCAN_BLOCKS) ? bsums[t] : 0;
    s[t] = v;
    __syncthreads();
    for (int off = 1; off < 256; off <<= 1) {
        int x = (t >= off) ? s[t - off] : 0;
        __syncthreads();
        s[t] += x;
        __syncthreads();
    }
    if (t < SCAN_BLOCKS) bsums[t] = s[t] - v;  // exclusive
}

__global__ __launch_bounds__(256) void k_scan3(const int* __restrict__ counts,
                                               int* __restrict__ rowst, const int* __restrict__ bsums) {
    int i = blockIdx.x * 256 + threadIdx.x;
    if (i < NN) rowst[i] = rowst[i] - counts[i] + bsums[blockIdx.x];
}

__global__ __launch_bounds__(256) void k_scatter2(const int* __restrict__ src, const int* __restrict__ dst,
                                                  const int* __restrict__ rank, const int* __restrict__ rowst,
                                                  int* __restrict__ ssrc) {
    int e = blockIdx.x * 256 + threadIdx.x;
    if (e < NE) ssrc[rowst[dst[e]] + rank[e]] = src[e];
}

// ---------- weight prep (one-time): transpose + bf16 hi/lo split ----------
__global__ __launch_bounds__(256) void k_wprep(const float* __restrict__ W1, const float* __restrict__ W2,
                                               const float* __restrict__ nW, const float* __restrict__ gW,
                                               const float* __restrict__ nbp, const float* __restrict__ gb,
                                               unsigned short* __restrict__ w1h, unsigned short* __restrict__ w1l,
                                               unsigned short* __restrict__ w2h, unsigned short* __restrict__ w2l,
                                               unsigned short* __restrict__ whh, unsigned short* __restrict__ whl,
                                               float* __restrict__ bc) {
    int i = blockIdx.x * 256 + threadIdx.x;
    if (i < 48 * 64) {
        int j = i >> 6, k = i & 63;
        float v = 0.f;
        if (j < ON) v = nW[k * ON + j];
        else if (j < 33) v = gW[k * OC + (j - ON)];
        unsigned short hi = f2b(v);
        whh[i] = hi;
        whl[i] = f2b(v - b2f(hi));
    }
    if (i < 48) bc[i] = (i < ON) ? nbp[i] : ((i < 33) ? gb[i - ON] : 0.f);
    if (i >= NL * H2 * HH) return;
    int l = i / (H2 * HH), r = i % (H2 * HH);
    {
        int c = r / HH, k = r % HH;
        float v = W1[(size_t)l * HH * H2 + (size_t)k * H2 + c];
        unsigned short hi = f2b(v);
        w1h[i] = hi;
        w1l[i] = f2b(v - b2f(hi));
    }
    {
        int c = r / H2, k = r % H2;
        float v = W2[(size_t)l * H2 * HH + (size_t)k * HH + c];
        unsigned short hi = f2b(v);
        w2h[i] = hi;
        w2l[i] = f2b(v - b2f(hi));
    }
}

// ---------- node encoder: h = x @ W + b  ([N,32]@[32,64]), also bf16 shadow ----------
__global__ __launch_bounds__(256) void k_encoder(const float* __restrict__ x, const float* __restrict__ W,
                                                 const float* __restrict__ b, float* __restrict__ h,
                                                 unsigned short* __restrict__ hbf) {
    __shared__ float Ws[INC * HH];
    __shared__ float bs[HH];
    int tid = threadIdx.x;
    for (int i = tid; i < INC * HH; i += 256) Ws[i] = W[i];
    if (tid < HH) bs[tid] = b[tid];
    __syncthreads();
    int wid = tid >> 6, lane = tid & 63;
    int n = blockIdx.x * 4 + wid;
    if (n >= NN) return;
    float v = (lane < INC) ? x[(size_t)n * INC + lane] : 0.f;
    float acc = bs[lane];
    #pragma unroll
    for (int k = 0; k < INC; ++k)
        acc += __shfl(v, k) * Ws[k * HH + lane];
    h[(size_t)n * HH + lane] = acc;
    hbf[(size_t)n * HH + lane] = f2b(acc);
}

// ---------- per-dst softmax aggregation, dual-row gathers ----------
__global__ __launch_bounds__(256) void k_agg(const float* __restrict__ y,
                                             const unsigned short* __restrict__ ybf,
                                             const int* __restrict__ rowst,
                                             const int* __restrict__ counts, const int* __restrict__ ssrc,
                                             const float* __restrict__ tp,
                                             unsigned short* __restrict__ agh,
                                             unsigned short* __restrict__ agl) {
    int tid = threadIdx.x;
    int wid = tid >> 6, lane = tid & 63;
    int n = blockIdx.x * 4 + wid;
    if (n >= NN) return;
    float tval = *tp;
    int start = rowst[n];
    int deg = counts[n];
    float Sa = 0.f, Sma = 0.f;
    if (deg > 0 && deg <= 64) {
        int myidx = (lane < deg) ? ssrc[start + lane] : 0;
        int half = lane >> 5;      // edge parity this lane handles
        int col = lane & 31;       // channel-pair index
        float Sa0 = 0.f, Sa1 = 0.f, Sm0 = 0.f, Sm1 = 0.f;
        for (int base = 0; base < deg; base += 16) {
            float c0[8], c1[8];
            int eidx[8];
            #pragma unroll
            for (int i = 0; i < 8; ++i) {
                int e = base + 2 * i + half;
                eidx[i] = e;
                int es = (e < deg) ? e : (deg - 1);
                int s = __shfl(myidx, es);
                unsigned v = *(const unsigned*)(ybf + (size_t)s * HH + col * 2);
                c0[i] = b2f((unsigned short)(v & 0xffffu));
                c1[i] = b2f((unsigned short)(v >> 16));
            }
            #pragma unroll
            for (int i = 0; i < 8; ++i) {
                bool ok = eidx[i] < deg;
                float m0 = fmaxf(c0[i], 0.f) + MEPS;
                float m1 = fmaxf(c1[i], 0.f) + MEPS;
                float a0 = ok ? __expf(tval * m0) : 0.f;
                float a1 = ok ? __expf(tval * m1) : 0.f;
                Sa0 += a0; Sm0 += m0 * a0;
                Sa1 += a1; Sm1 += m1 * a1;
            }
        }
        Sa0 += __shfl_xor(Sa0, 32); Sa1 += __shfl_xor(Sa1, 32);
        Sm0 += __shfl_xor(Sm0, 32); Sm1 += __shfl_xor(Sm1, 32);
        int srcl = lane >> 1;
        float saA = __shfl(Sa0, srcl), saB = __shfl(Sa1, srcl);
        float smA = __shfl(Sm0, srcl), smB = __shfl(Sm1, srcl);
        Sa = (lane & 1) ? saB : saA;
        Sma = (lane & 1) ? smB : smA;
    } else if (deg > 64) {
        for (int e = 0; e < deg; ++e) {
            int s = ssrc[start + e];
            float v = b2f(ybf[(size_t)s * HH + lane]);
            float m = fmaxf(v, 0.f) + MEPS;
            float a = __expf(tval * m);
            Sa += a; Sma += m * a;
        }
    }
    float agg = Sma / fmaxf(Sa, MEPS);  // deg==0 -> 0
    float av = agg + y[(size_t)n * HH + lane];
    unsigned short hi = f2b(av);
    agh[(size_t)n * HH + lane] = hi;
    agl[(size_t)n * HH + lane] = f2b(av - b2f(hi));
}

// ---------- MFMA fused MLP, swapped-operand form; zero block barriers ----------
__global__ __launch_bounds__(256) void k_mlp(
    const unsigned short* __restrict__ agh, const unsigned short* __restrict__ agl,
    const unsigned short* __restrict__ w1h, const unsigned short* __restrict__ w1l,
    const float* __restrict__ b1,
    const float* __restrict__ mlg, const float* __restrict__ mlb,
    const unsigned short* __restrict__ w2h, const unsigned short* __restrict__ w2l,
    const float* __restrict__ b2,
    const float* __restrict__ hres, float* __restrict__ hout,
    const float* __restrict__ lng1, const float* __restrict__ lnb1,
    float* __restrict__ y, unsigned short* __restrict__ ybf)
{
    __shared__ __align__(16) unsigned short Ut[4][16 * 136];  // stride 136 shorts: bank-stagger
    int tid = threadIdx.x;
    int w = tid >> 6, lane = tid & 63;
    int nl = lane & 15, g = lane >> 4;
    int node = blockIdx.x * 64 + w * 16 + nl;
    bool valid = node < NN;

    // B-frags for gemmA: ag^T tile; B[k][j]: j=lane&15=node, k=(lane>>4)*8+e
    bf16x8 bAh[2], bAl[2];
    {
        bf16x8 z = {0, 0, 0, 0, 0, 0, 0, 0};
        if (valid) {
            const unsigned short* rp = agh + (size_t)node * HH + g * 8;
            bAh[0] = *(const bf16x8*)rp;
            bAh[1] = *(const bf16x8*)(rp + 32);
            const unsigned short* rq = agl + (size_t)node * HH + g * 8;
            bAl[0] = *(const bf16x8*)rq;
            bAl[1] = *(const bf16x8*)(rq + 32);
        } else {
            bAh[0] = z; bAh[1] = z; bAl[0] = z; bAl[1] = z;
        }
    }

    // gemmA: U^T tiles (8 x 16 ucols), K=64. 3 MFMA per (t,kc)
    f32x4 accU[8];
    #pragma unroll
    for (int t = 0; t < 8; ++t) {
        int uc = t * 16 + g * 4;
        float4 bb = *(const float4*)(b1 + uc);
        f32x4 a = {bb.x, bb.y, bb.z, bb.w};
        #pragma unroll
        for (int kc = 0; kc < 2; ++kc) {
            size_t wo = (size_t)(t * 16 + nl) * 64 + kc * 32 + g * 8;
            bf16x8 ah = *(const bf16x8*)(w1h + wo);
            bf16x8 al = *(const bf16x8*)(w1l + wo);
            a = __builtin_amdgcn_mfma_f32_16x16x32_bf16(ah, bAh[kc], a, 0, 0, 0);
            a = __builtin_amdgcn_mfma_f32_16x16x32_bf16(al, bAh[kc], a, 0, 0, 0);
            a = __builtin_amdgcn_mfma_f32_16x16x32_bf16(ah, bAl[kc], a, 0, 0, 0);
        }
        accU[t] = a;
    }

    // LN(128): node = lane&15 -> reduce in-lane + across the 4 lane-groups
    float s = 0.f, sq = 0.f;
    #pragma unroll
    for (int t = 0; t < 8; ++t) {
        #pragma unroll
        for (int j = 0; j < 4; ++j) { float v = accU[t][j]; s += v; sq += v * v; }
    }
    s += __shfl_xor(s, 16); sq += __shfl_xor(sq, 16);
    s += __shfl_xor(s, 32); sq += __shfl_xor(sq, 32);
    float mu = s * (1.f / 128.f);
    float var = sq * (1.f / 128.f) - mu * mu;
    float rs = rsqrtf(fmaxf(var, 0.f) + LNE);

    // normalize + relu + pack bf16 -> Ut[node][ucol]
    #pragma unroll
    for (int t = 0; t < 8; ++t) {
        int uc = t * 16 + g * 4;
        float4 gg = *(const float4*)(mlg + uc);
        float4 bb = *(const float4*)(mlb + uc);
        ushort4 pk;
        pk.x = f2b(fmaxf((accU[t][0] - mu) * rs * gg.x + bb.x, 0.f));
        pk.y = f2b(fmaxf((accU[t][1] - mu) * rs * gg.y + bb.y, 0.f));
        pk.z = f2b(fmaxf((accU[t][2] - mu) * rs * gg.z + bb.z, 0.f));
        pk.w = f2b(fmaxf((accU[t][3] - mu) * rs * gg.w + bb.w, 0.f));
        *(ushort4*)(&Ut[w][nl * 136 + uc]) = pk;
    }
    // cross-LANE (same wave) LDS dependency: drain our wave's ds_writes
    asm volatile("s_waitcnt lgkmcnt(0)" ::: "memory");

    // B-frags for gemmB: P^T
    bf16x8 bB[4];
    #pragma unroll
    for (int kc = 0; kc < 4; ++kc)
        bB[kc] = *(const bf16x8*)(&Ut[w][nl * 136 + kc * 32 + g * 8]);

    // gemmB: O^T tiles (4 x 16 ocols), K=128. 2 MFMA per (ot,kc)
    f32x4 accO[4];
    #pragma unroll
    for (int ot = 0; ot < 4; ++ot) {
        int oc = ot * 16 + g * 4;
        float4 bb = *(const float4*)(b2 + oc);
        f32x4 a = {bb.x, bb.y, bb.z, bb.w};
        #pragma unroll
        for (int kc = 0; kc < 4; ++kc) {
            size_t wo = (size_t)(ot * 16 + nl) * 128 + kc * 32 + g * 8;
            bf16x8 ah = *(const bf16x8*)(w2h + wo);
            bf16x8 al = *(const bf16x8*)(w2l + wo);
            a = __builtin_amdgcn_mfma_f32_16x16x32_bf16(ah, bB[kc], a, 0, 0, 0);
            a = __builtin_amdgcn_mfma_f32_16x16x32_bf16(al, bB[kc], a, 0, 0, 0);
        }
        accO[ot] = a;
    }

    // epilogue: +residual, write h
    float4 oo[4];
    #pragma unroll
    for (int ot = 0; ot < 4; ++ot) {
        int oc = ot * 16 + g * 4;
        float4 o;
        o.x = accO[ot][0]; o.y = accO[ot][1]; o.z = accO[ot][2]; o.w = accO[ot][3];
        if (valid) {
            if (hres) {
                float4 hr = *(const float4*)(hres + (size_t)node * HH + oc);
                o.x += hr.x; o.y += hr.y; o.z += hr.z; o.w += hr.w;
            }
            *(float4*)(hout + (size_t)node * HH + oc) = o;
        }
        oo[ot] = o;
    }
    if (!lng1) return;   // last layer: k_outg does the final LN (uniform exit)

    // next-layer LN(64)+ReLU, all in registers
    float s2 = 0.f, sq2 = 0.f;
    #pragma unroll
    for (int ot = 0; ot < 4; ++ot) {
        s2 += oo[ot].x + oo[ot].y + oo[ot].z + oo[ot].w;
        sq2 += oo[ot].x * oo[ot].x + oo[ot].y * oo[ot].y
             + oo[ot].z * oo[ot].z + oo[ot].w * oo[ot].w;
    }
    s2 += __shfl_xor(s2, 16); sq2 += __shfl_xor(sq2, 16);
    s2 += __shfl_xor(s2, 32); sq2 += __shfl_xor(sq2, 32);
    float mu2 = s2 * (1.f / 64.f);
    float var2 = sq2 * (1.f / 64.f) - mu2 * mu2;
    float rs2 = rsqrtf(fmaxf(var2, 0.f) + LNE);
    #pragma unroll
    for (int ot = 0; ot < 4; ++ot) {
        int oc = ot * 16 + g * 4;
        float4 gg = *(const float4*)(lng1 + oc);
        float4 bb = *(const float4*)(lnb1 + oc);
        float4 v;
        v.x = fmaxf((oo[ot].x - mu2) * rs2 * gg.x + bb.x, 0.f);
        v.y = fmaxf((oo[ot].y - mu2) * rs2 * gg.y + bb.y, 0.f);
        v.z = fmaxf((oo[ot].z - mu2) * rs2 * gg.z + bb.z, 0.f);
        v.w = fmaxf((oo[ot].w - mu2) * rs2 * gg.w + bb.w, 0.f);
        if (valid) {
            *(float4*)(y + (size_t)node * HH + oc) = v;
            ushort4 p;
            p.x = f2b(v.x); p.y = f2b(v.y); p.z = f2b(v.z); p.w = f2b(v.w);
            *(ushort4*)(ybf + (size_t)node * HH + oc) = p;
        }
    }
}

// ---------- MFMA final LN + both heads; g-head via dense per-block max (NO atomics) ----------
// Round-6 lesson: ~50k atomicMax to one 64B line serialized at ~3.7ns each = 186us.
// Two-stage: block-max -> gmax[block][16] (dense stores), k_gdec reduces 782x16.
__global__ __launch_bounds__(256) void k_outg(const float* __restrict__ h,
                                              const float* __restrict__ lng, const float* __restrict__ lnb,
                                              const unsigned short* __restrict__ whh,
                                              const unsigned short* __restrict__ whl,
                                              const float* __restrict__ bc,
                                              float* __restrict__ dout, float* __restrict__ gmax) {
    __shared__ float smax[4][16];
    int tid = threadIdx.x;
    int w = tid >> 6, lane = tid & 63;
    int nl = lane & 15, g = lane >> 4;
    int node = blockIdx.x * 64 + w * 16 + nl;
    bool valid = node < NN;

    // load h chunks: k = kc*32 + g*8 + e
    float hv[16];
    if (valid) {
        const float* hp = h + (size_t)node * HH;
        float4 a0 = *(const float4*)(hp + g * 8);
        float4 a1 = *(const float4*)(hp + g * 8 + 4);
        float4 a2 = *(const float4*)(hp + 32 + g * 8);
        float4 a3 = *(const float4*)(hp + 32 + g * 8 + 4);
        hv[0] = a0.x; hv[1] = a0.y; hv[2] = a0.z; hv[3] = a0.w;
        hv[4] = a1.x; hv[5] = a1.y; hv[6] = a1.z; hv[7] = a1.w;
        hv[8] = a2.x; hv[9] = a2.y; hv[10] = a2.z; hv[11] = a2.w;
        hv[12] = a3.x; hv[13] = a3.y; hv[14] = a3.z; hv[15] = a3.w;
    } else {
        #pragma unroll
        for (int i = 0; i < 16; ++i) hv[i] = 0.f;
    }

    // LN(64) stats: in-lane + combine the 4 g-groups (nl preserved)
    float s = 0.f, sq = 0.f;
    #pragma unroll
    for (int i = 0; i < 16; ++i) { s += hv[i]; sq += hv[i] * hv[i]; }
    s += __shfl_xor(s, 16); sq += __shfl_xor(sq, 16);
    s += __shfl_xor(s, 32); sq += __shfl_xor(sq, 32);
    float mu = s * (1.f / 64.f);
    float var = sq * (1.f / 64.f) - mu * mu;
    float rs = rsqrtf(fmaxf(var, 0.f) + LNE);

    // normalize + relu, pack bf16 hi/lo B-frags
    union { bf16x8 v; unsigned short u[8]; } Bh[2], Bl[2];
    #pragma unroll
    for (int kc = 0; kc < 2; ++kc) {
        int cb = kc * 32 + g * 8;
        float4 g0 = *(const float4*)(lng + cb);
        float4 g1 = *(const float4*)(lng + cb + 4);
        float4 b0 = *(const float4*)(lnb + cb);
        float4 b1v = *(const float4*)(lnb + cb + 4);
        float gv[8] = {g0.x, g0.y, g0.z, g0.w, g1.x, g1.y, g1.z, g1.w};
        float bv[8] = {b0.x, b0.y, b0.z, b0.w, b1v.x, b1v.y, b1v.z, b1v.w};
        #pragma unroll
        for (int e = 0; e < 8; ++e) {
            float v = fmaxf((hv[kc * 8 + e] - mu) * rs * gv[e] + bv[e], 0.f);
            unsigned short hi = f2b(v);
            Bh[kc].u[e] = hi;
            Bl[kc].u[e] = f2b(v - b2f(hi));
        }
    }

    // heads: 3 output tiles (j = t*16 + g*4 + reg), K=64, 3 MFMA per (t,kc)
    f32x4 acc[3];
    #pragma unroll
    for (int t = 0; t < 3; ++t) {
        int j0 = t * 16 + g * 4;
        float4 bb = *(const float4*)(bc + j0);
        f32x4 a = {bb.x, bb.y, bb.z, bb.w};
        #pragma unroll
        for (int kc = 0; kc < 2; ++kc) {
            size_t wo = (size_t)(t * 16 + nl) * 64 + kc * 32 + g * 8;
            bf16x8 ah = *(const bf16x8*)(whh + wo);
            bf16x8 al = *(const bf16x8*)(whl + wo);
            a = __builtin_amdgcn_mfma_f32_16x16x32_bf16(ah, Bh[kc].v, a, 0, 0, 0);
            a = __builtin_amdgcn_mfma_f32_16x16x32_bf16(al, Bh[kc].v, a, 0, 0, 0);
            a = __builtin_amdgcn_mfma_f32_16x16x32_bf16(ah, Bl[kc].v, a, 0, 0, 0);
        }
        acc[t] = a;
    }

    // n-head direct stores; g-head butterfly-max over node-lanes -> LDS -> block max
    #pragma unroll
    for (int t = 0; t < 3; ++t) {
        #pragma unroll
        for (int reg = 0; reg < 4; ++reg) {
            int j = t * 16 + g * 4 + reg;   // uniform within a g-group
            float val = acc[t][reg];
            if (j < ON) {
                if (valid) dout[OC + (size_t)node * ON + j] = val;
            } else if (j < 33) {
                float gv = valid ? val : -INFINITY;
                #pragma unroll
                for (int m = 1; m < 16; m <<= 1) gv = fmaxf(gv, __shfl_xor(gv, m));
                if (nl == 0) smax[w][j - ON] = gv;
            }
        }
    }
    __syncthreads();
    if (tid < 16) {
        float m = fmaxf(fmaxf(smax[0][tid], smax[1][tid]),
                        fmaxf(smax[2][tid], smax[3][tid]));
        gmax[(size_t)blockIdx.x * 16 + tid] = m;
    }
}

// 1-wave final reduce: gmax[NOB][16] -> dout[0..15]
__global__ void k_gdec(const float* __restrict__ gmax, float* __restrict__ dout) {
    int lane = threadIdx.x & 63;
    int ch = lane & 15, grp = lane >> 4;   // 4 groups stride over blocks
    float m = -INFINITY;
    for (int b = grp; b < NOB; b += 4) m = fmaxf(m, gmax[(size_t)b * 16 + ch]);
    m = fmaxf(m, __shfl_xor(m, 16));
    m = fmaxf(m, __shfl_xor(m, 32));
    if (lane < 16) dout[ch] = m;
}

// ---------- launch ----------
extern "C" void kernel_launch(void* const* d_in, const int* in_sizes, int n_in,
                              void* d_out, int out_size, void* d_ws, size_t ws_size,
                              hipStream_t stream) {
    const float* x     = (const float*)d_in[0];
    const float* nodeW = (const float*)d_in[1];
    const float* nodeB = (const float*)d_in[2];
    const float* W1    = (const float*)d_in[3];
    const float* b1    = (const float*)d_in[4];
    const float* mlg   = (const float*)d_in[5];
    const float* mlb   = (const float*)d_in[6];
    const float* W2    = (const float*)d_in[7];
    const float* b2    = (const float*)d_in[8];
    const float* tt    = (const float*)d_in[9];
    const float* lng   = (const float*)d_in[10];
    const float* lnb   = (const float*)d_in[11];
    const int*   ei    = (const int*)d_in[12];
    const float* gW    = (const float*)d_in[13];
    const float* gb    = (const float*)d_in[14];
    const float* nW    = (const float*)d_in[15];
    const float* nbp   = (const float*)d_in[16];
    float* out = (float*)d_out;

    char* ws = (char*)d_ws;
    size_t off = 0;
    auto alloc = [&](size_t bytes) -> void* {
        void* p = ws + off;
        off = (off + bytes + 255) & ~(size_t)255;
        return p;
    };
    int* counts    = (int*)alloc((size_t)NN * 4);
    size_t zero_end = off;
    float* gmax = (float*)alloc((size_t)NOB * 16 * 4);
    int* bsums = (int*)alloc(1024);
    int* rowst = (int*)alloc((size_t)NN * 4);
    int* ssrc  = (int*)alloc((size_t)NE * 4);
    float* h   = (float*)alloc((size_t)NN * HH * 4);
    float* y   = (float*)alloc((size_t)NN * HH * 4);
    unsigned short* agh = (unsigned short*)alloc((size_t)NN * HH * 2);
    unsigned short* agl = (unsigned short*)alloc((size_t)NN * HH * 2);
    unsigned short* ybf = (unsigned short*)alloc((size_t)NN * HH * 2);
    unsigned short* w1h = (unsigned short*)alloc((size_t)NL * H2 * HH * 2);
    unsigned short* w1l = (unsigned short*)alloc((size_t)NL * H2 * HH * 2);
    unsigned short* w2h = (unsigned short*)alloc((size_t)NL * H2 * HH * 2);
    unsigned short* w2l = (unsigned short*)alloc((size_t)NL * H2 * HH * 2);
    unsigned short* whh = (unsigned short*)alloc((size_t)48 * 64 * 2);
    unsigned short* whl = (unsigned short*)alloc((size_t)48 * 64 * 2);
    float* bc = (float*)alloc(48 * 4);
    int* rank = (int*)agh;   // alias: rank only lives during CSR build (3.2MB <= 6.4MB)

    const int* esrc = ei;
    const int* edst = ei + NE;

    hipMemsetAsync(d_ws, 0, zero_end, stream);

    k_wprep<<<(NL * H2 * HH + 255) / 256, 256, 0, stream>>>(W1, W2, nW, gW, nbp, gb,
                                                            w1h, w1l, w2h, w2l, whh, whl, bc);
    k_hist2<<<(NE + 255) / 256, 256, 0, stream>>>(edst, counts, rank);
    k_scan1<<<SCAN_BLOCKS, 256, 0, stream>>>(counts, rowst, bsums);
    k_scan2<<<1, 256, 0, stream>>>(bsums);
    k_scan3<<<SCAN_BLOCKS, 256, 0, stream>>>(counts, rowst, bsums);
    k_scatter2<<<(NE + 255) / 256, 256, 0, stream>>>(esrc, edst, rank, rowst, ssrc);
    k_encoder<<<(NN + 3) / 4, 256, 0, stream>>>(x, nodeW, nodeB, h, ybf);

    for (int l = 0; l < NL; ++l) {
        const float* yin = (l == 0) ? h : y;
        k_agg<<<(NN + 3) / 4, 256, 0, stream>>>(yin, ybf, rowst, counts, ssrc, tt + l, agh, agl);
        const float* ln1g = (l < NL - 1) ? (lng + (size_t)(l + 1) * HH) : nullptr;
        const float* ln1b = (l < NL - 1) ? (lnb + (size_t)(l + 1) * HH) : nullptr;
        k_mlp<<<(NN + 63) / 64, 256, 0, stream>>>(agh, agl,
                                                  w1h + (size_t)l * H2 * HH, w1l + (size_t)l * H2 * HH,
                                                  b1 + (size_t)l * H2,
                                                  mlg + (size_t)l * H2, mlb + (size_t)l * H2,
                                                  w2h + (size_t)l * H2 * HH, w2l + (size_t)l * H2 * HH,
                                                  b2 + (size_t)l * HH,
                                                  (l == 0) ? (const float*)nullptr : h, h,
                                                  ln1g, ln1b, y, ybf);
    }
    k_outg<<<NOB, 256, 0, stream>>>(h, lng, lnb, whh, whl, bc, out, gmax);
    k_gdec<<<1, 64, 0, stream>>>(gmax, out);
}

// Round 9
// 418.021 us; speedup vs baseline: 1.5700x; 1.2155x over previous
//
#include <hip/hip_runtime.h>

#define NN 50000
#define NE 800000
#define INC 32
#define HH 64
#define H2 128
#define OC 16
#define ON 17
#define NL 4
#define MEPS 1e-7f
#define LNE 1e-5f
#define SCAN_BLOCKS 196   /* ceil(50000/256) */
#define NOB ((NN + 63) / 64)   /* k_outg blocks = 782 */

typedef __attribute__((ext_vector_type(8))) short bf16x8;
typedef __attribute__((ext_vector_type(4))) float f32x4;

// ---------- bf16 helpers (RNE) ----------
__device__ __forceinline__ unsigned short f2b(float x) {
    unsigned b = __float_as_uint(x);
    b += 0x7FFFu + ((b >> 16) & 1u);
    return (unsigned short)(b >> 16);
}
__device__ __forceinline__ float b2f(unsigned short u) {
    return __uint_as_float(((unsigned)u) << 16);
}

// ---------- CSR build ----------
__global__ __launch_bounds__(256) void k_hist2(const int* __restrict__ dst, int* __restrict__ counts,
                                               int* __restrict__ rank) {
    int e = blockIdx.x * 256 + threadIdx.x;
    if (e < NE) rank[e] = atomicAdd(&counts[dst[e]], 1);
}

__global__ __launch_bounds__(256) void k_scan1(const int* __restrict__ counts,
                                               int* __restrict__ incl, int* __restrict__ bsums) {
    __shared__ int s[256];
    int t = threadIdx.x;
    int i = blockIdx.x * 256 + t;
    int v = (i < NN) ? counts[i] : 0;
    s[t] = v;
    __syncthreads();
    for (int off = 1; off < 256; off <<= 1) {
        int x = (t >= off) ? s[t - off] : 0;
        __syncthreads();
        s[t] += x;
        __syncthreads();
    }
    if (i < NN) incl[i] = s[t];
    if (t == 255) bsums[blockIdx.x] = s[255];
}

__global__ __launch_bounds__(256) void k_scan2(int* __restrict__ bsums) {
    __shared__ int s[256];
    int t = threadIdx.x;
    int v = (t < SCAN_BLOCKS) ? bsums[t] : 0;
    s[t] = v;
    __syncthreads();
    for (int off = 1; off < 256; off <<= 1) {
        int x = (t >= off) ? s[t - off] : 0;
        __syncthreads();
        s[t] += x;
        __syncthreads();
    }
    if (t < SCAN_BLOCKS) bsums[t] = s[t] - v;  // exclusive
}

__global__ __launch_bounds__(256) void k_scan3(const int* __restrict__ counts,
                                               int* __restrict__ rowst, const int* __restrict__ bsums) {
    int i = blockIdx.x * 256 + threadIdx.x;
    if (i < NN) rowst[i] = rowst[i] - counts[i] + bsums[blockIdx.x];
}

__global__ __launch_bounds__(256) void k_scatter2(const int* __restrict__ src, const int* __restrict__ dst,
                                                  const int* __restrict__ rank, const int* __restrict__ rowst,
                                                  int* __restrict__ ssrc) {
    int e = blockIdx.x * 256 + threadIdx.x;
    if (e < NE) ssrc[rowst[dst[e]] + rank[e]] = src[e];
}

// ---------- weight prep (one-time): transpose + bf16 hi/lo split ----------
__global__ __launch_bounds__(256) void k_wprep(const float* __restrict__ W1, const float* __restrict__ W2,
                                               const float* __restrict__ nW, const float* __restrict__ gW,
                                               const float* __restrict__ nbp, const float* __restrict__ gb,
                                               unsigned short* __restrict__ w1h, unsigned short* __restrict__ w1l,
                                               unsigned short* __restrict__ w2h, unsigned short* __restrict__ w2l,
                                               unsigned short* __restrict__ whh, unsigned short* __restrict__ whl,
                                               float* __restrict__ bc) {
    int i = blockIdx.x * 256 + threadIdx.x;
    if (i < 48 * 64) {
        int j = i >> 6, k = i & 63;
        float v = 0.f;
        if (j < ON) v = nW[k * ON + j];
        else if (j < 33) v = gW[k * OC + (j - ON)];
        unsigned short hi = f2b(v);
        whh[i] = hi;
        whl[i] = f2b(v - b2f(hi));
    }
    if (i < 48) bc[i] = (i < ON) ? nbp[i] : ((i < 33) ? gb[i - ON] : 0.f);
    if (i >= NL * H2 * HH) return;
    int l = i / (H2 * HH), r = i % (H2 * HH);
    {
        int c = r / HH, k = r % HH;
        float v = W1[(size_t)l * HH * H2 + (size_t)k * H2 + c];
        unsigned short hi = f2b(v);
        w1h[i] = hi;
        w1l[i] = f2b(v - b2f(hi));
    }
    {
        int c = r / H2, k = r % H2;
        float v = W2[(size_t)l * H2 * HH + (size_t)k * HH + c];
        unsigned short hi = f2b(v);
        w2h[i] = hi;
        w2l[i] = f2b(v - b2f(hi));
    }
}

// ---------- node encoder: h = x @ W + b  ([N,32]@[32,64]), also bf16 shadow ----------
__global__ __launch_bounds__(256) void k_encoder(const float* __restrict__ x, const float* __restrict__ W,
                                                 const float* __restrict__ b, float* __restrict__ h,
                                                 unsigned short* __restrict__ hbf) {
    __shared__ float Ws[INC * HH];
    __shared__ float bs[HH];
    int tid = threadIdx.x;
    for (int i = tid; i < INC * HH; i += 256) Ws[i] = W[i];
    if (tid < HH) bs[tid] = b[tid];
    __syncthreads();
    int wid = tid >> 6, lane = tid & 63;
    int n = blockIdx.x * 4 + wid;
    if (n >= NN) return;
    float v = (lane < INC) ? x[(size_t)n * INC + lane] : 0.f;
    float acc = bs[lane];
    #pragma unroll
    for (int k = 0; k < INC; ++k)
        acc += __shfl(v, k) * Ws[k * HH + lane];
    h[(size_t)n * HH + lane] = acc;
    hbf[(size_t)n * HH + lane] = f2b(acc);
}

// ---------- per-dst softmax aggregation, dual-row gathers ----------
__global__ __launch_bounds__(256) void k_agg(const float* __restrict__ y,
                                             const unsigned short* __restrict__ ybf,
                                             const int* __restrict__ rowst,
                                             const int* __restrict__ counts, const int* __restrict__ ssrc,
                                             const float* __restrict__ tp,
                                             unsigned short* __restrict__ agh,
                                             unsigned short* __restrict__ agl) {
    int tid = threadIdx.x;
    int wid = tid >> 6, lane = tid & 63;
    int n = blockIdx.x * 4 + wid;
    if (n >= NN) return;
    float tval = *tp;
    int start = rowst[n];
    int deg = counts[n];
    float Sa = 0.f, Sma = 0.f;
    if (deg > 0 && deg <= 64) {
        int myidx = (lane < deg) ? ssrc[start + lane] : 0;
        int half = lane >> 5;      // edge parity this lane handles
        int col = lane & 31;       // channel-pair index
        float Sa0 = 0.f, Sa1 = 0.f, Sm0 = 0.f, Sm1 = 0.f;
        for (int base = 0; base < deg; base += 16) {
            float c0[8], c1[8];
            int eidx[8];
            #pragma unroll
            for (int i = 0; i < 8; ++i) {
                int e = base + 2 * i + half;
                eidx[i] = e;
                int es = (e < deg) ? e : (deg - 1);
                int s = __shfl(myidx, es);
                unsigned v = *(const unsigned*)(ybf + (size_t)s * HH + col * 2);
                c0[i] = b2f((unsigned short)(v & 0xffffu));
                c1[i] = b2f((unsigned short)(v >> 16));
            }
            #pragma unroll
            for (int i = 0; i < 8; ++i) {
                bool ok = eidx[i] < deg;
                float m0 = fmaxf(c0[i], 0.f) + MEPS;
                float m1 = fmaxf(c1[i], 0.f) + MEPS;
                float a0 = ok ? __expf(tval * m0) : 0.f;
                float a1 = ok ? __expf(tval * m1) : 0.f;
                Sa0 += a0; Sm0 += m0 * a0;
                Sa1 += a1; Sm1 += m1 * a1;
            }
        }
        Sa0 += __shfl_xor(Sa0, 32); Sa1 += __shfl_xor(Sa1, 32);
        Sm0 += __shfl_xor(Sm0, 32); Sm1 += __shfl_xor(Sm1, 32);
        int srcl = lane >> 1;
        float saA = __shfl(Sa0, srcl), saB = __shfl(Sa1, srcl);
        float smA = __shfl(Sm0, srcl), smB = __shfl(Sm1, srcl);
        Sa = (lane & 1) ? saB : saA;
        Sma = (lane & 1) ? smB : smA;
    } else if (deg > 64) {
        for (int e = 0; e < deg; ++e) {
            int s = ssrc[start + e];
            float v = b2f(ybf[(size_t)s * HH + lane]);
            float m = fmaxf(v, 0.f) + MEPS;
            float a = __expf(tval * m);
            Sa += a; Sma += m * a;
        }
    }
    float agg = Sma / fmaxf(Sa, MEPS);  // deg==0 -> 0
    float av = agg + y[(size_t)n * HH + lane];
    unsigned short hi = f2b(av);
    agh[(size_t)n * HH + lane] = hi;
    agl[(size_t)n * HH + lane] = f2b(av - b2f(hi));
}

// ---------- MFMA fused MLP with LDS-staged weights ----------
// Round-7 lesson: per-wave fragment loads from L2 serialize (VGPR=44, no prefetch
// headroom -> ~64 x 250cy dependent round trips = 46us at 12% HBM / 3% MFMA).
// Fix: block-cooperative coalesced staging of W1/W2 hi+lo into LDS (70KB, 2 blocks/CU);
// fragment reads become ds_read_b128. Ut aliases W1hi space after gemmA (one barrier).
__global__ __launch_bounds__(256) void k_mlp(
    const unsigned short* __restrict__ agh, const unsigned short* __restrict__ agl,
    const unsigned short* __restrict__ w1h, const unsigned short* __restrict__ w1l,
    const float* __restrict__ b1,
    const float* __restrict__ mlg, const float* __restrict__ mlb,
    const unsigned short* __restrict__ w2h, const unsigned short* __restrict__ w2l,
    const float* __restrict__ b2,
    const float* __restrict__ hres, float* __restrict__ hout,
    const float* __restrict__ lng1, const float* __restrict__ lnb1,
    float* __restrict__ y, unsigned short* __restrict__ ybf)
{
    __shared__ __align__(16) unsigned short W1hS[128 * 72];   // 18432B; Ut aliases here later
    __shared__ __align__(16) unsigned short W1lS[128 * 72];
    __shared__ __align__(16) unsigned short W2hS[64 * 136];   // 17408B
    __shared__ __align__(16) unsigned short W2lS[64 * 136];
    int tid = threadIdx.x;
    int w = tid >> 6, lane = tid & 63;
    int nl = lane & 15, g = lane >> 4;
    int node = blockIdx.x * 64 + w * 16 + nl;
    bool valid = node < NN;

    // ---- issue ag loads FIRST (HBM latency hides under weight staging)
    bf16x8 bAh[2], bAl[2];
    {
        bf16x8 z = {0, 0, 0, 0, 0, 0, 0, 0};
        if (valid) {
            const unsigned short* rp = agh + (size_t)node * HH + g * 8;
            bAh[0] = *(const bf16x8*)rp;
            bAh[1] = *(const bf16x8*)(rp + 32);
            const unsigned short* rq = agl + (size_t)node * HH + g * 8;
            bAl[0] = *(const bf16x8*)rq;
            bAl[1] = *(const bf16x8*)(rq + 32);
        } else {
            bAh[0] = z; bAh[1] = z; bAl[0] = z; bAl[1] = z;
        }
    }

    // ---- cooperative weight staging: 16 coalesced 16B loads/thread
    #pragma unroll
    for (int it = 0; it < 4; ++it) {                 // W1: 1024 chunks, row=c>>3
        int c = tid + it * 256;
        int row = c >> 3, col = (c & 7) << 3;
        float4 vh = *(const float4*)(w1h + c * 8);
        float4 vl = *(const float4*)(w1l + c * 8);
        *(float4*)&W1hS[row * 72 + col] = vh;
        *(float4*)&W1lS[row * 72 + col] = vl;
    }
    #pragma unroll
    for (int it = 0; it < 4; ++it) {                 // W2: 1024 chunks, row=c>>4
        int c = tid + it * 256;
        int row = c >> 4, col = (c & 15) << 3;
        float4 vh = *(const float4*)(w2h + c * 8);
        float4 vl = *(const float4*)(w2l + c * 8);
        *(float4*)&W2hS[row * 136 + col] = vh;
        *(float4*)&W2lS[row * 136 + col] = vl;
    }
    __syncthreads();

    // ---- gemmA: U^T tiles (8 x 16 ucols), K=64. 3 MFMA per (t,kc), frags from LDS
    f32x4 accU[8];
    #pragma unroll
    for (int t = 0; t < 8; ++t) {
        int uc = t * 16 + g * 4;
        float4 bb = *(const float4*)(b1 + uc);
        f32x4 a = {bb.x, bb.y, bb.z, bb.w};
        #pragma unroll
        for (int kc = 0; kc < 2; ++kc) {
            int wo = (t * 16 + nl) * 72 + kc * 32 + g * 8;
            bf16x8 ah = *(const bf16x8*)&W1hS[wo];
            bf16x8 al = *(const bf16x8*)&W1lS[wo];
            a = __builtin_amdgcn_mfma_f32_16x16x32_bf16(ah, bAh[kc], a, 0, 0, 0);
            a = __builtin_amdgcn_mfma_f32_16x16x32_bf16(al, bAh[kc], a, 0, 0, 0);
            a = __builtin_amdgcn_mfma_f32_16x16x32_bf16(ah, bAl[kc], a, 0, 0, 0);
        }
        accU[t] = a;
    }

    // ---- LN(128): node = lane&15 -> in-lane + 2 shfl_xor
    float s = 0.f, sq = 0.f;
    #pragma unroll
    for (int t = 0; t < 8; ++t) {
        #pragma unroll
        for (int j = 0; j < 4; ++j) { float v = accU[t][j]; s += v; sq += v * v; }
    }
    s += __shfl_xor(s, 16); sq += __shfl_xor(sq, 16);
    s += __shfl_xor(s, 32); sq += __shfl_xor(sq, 32);
    float mu = s * (1.f / 128.f);
    float var = sq * (1.f / 128.f) - mu * mu;
    float rs = rsqrtf(fmaxf(var, 0.f) + LNE);

    __syncthreads();   // all waves done reading W1 LDS -> Ut may overwrite it
    unsigned short* myUt = W1hS + w * (16 * 136);   // 4352B/wave, 16B-aligned

    // normalize + relu + pack bf16 -> myUt[node][ucol]
    #pragma unroll
    for (int t = 0; t < 8; ++t) {
        int uc = t * 16 + g * 4;
        float4 gg = *(const float4*)(mlg + uc);
        float4 bb = *(const float4*)(mlb + uc);
        ushort4 pk;
        pk.x = f2b(fmaxf((accU[t][0] - mu) * rs * gg.x + bb.x, 0.f));
        pk.y = f2b(fmaxf((accU[t][1] - mu) * rs * gg.y + bb.y, 0.f));
        pk.z = f2b(fmaxf((accU[t][2] - mu) * rs * gg.z + bb.z, 0.f));
        pk.w = f2b(fmaxf((accU[t][3] - mu) * rs * gg.w + bb.w, 0.f));
        *(ushort4*)(&myUt[nl * 136 + uc]) = pk;
    }
    // per-wave slice: only our own wave's writes must land before our reads
    asm volatile("s_waitcnt lgkmcnt(0)" ::: "memory");

    // B-frags for gemmB: P^T
    bf16x8 bB[4];
    #pragma unroll
    for (int kc = 0; kc < 4; ++kc)
        bB[kc] = *(const bf16x8*)(&myUt[nl * 136 + kc * 32 + g * 8]);

    // gemmB: O^T tiles (4 x 16 ocols), K=128. 2 MFMA per (ot,kc), frags from LDS
    f32x4 accO[4];
    #pragma unroll
    for (int ot = 0; ot < 4; ++ot) {
        int oc = ot * 16 + g * 4;
        float4 bb = *(const float4*)(b2 + oc);
        f32x4 a = {bb.x, bb.y, bb.z, bb.w};
        #pragma unroll
        for (int kc = 0; kc < 4; ++kc) {
            int wo = (ot * 16 + nl) * 136 + kc * 32 + g * 8;
            bf16x8 ah = *(const bf16x8*)&W2hS[wo];
            bf16x8 al = *(const bf16x8*)&W2lS[wo];
            a = __builtin_amdgcn_mfma_f32_16x16x32_bf16(ah, bB[kc], a, 0, 0, 0);
            a = __builtin_amdgcn_mfma_f32_16x16x32_bf16(al, bB[kc], a, 0, 0, 0);
        }
        accO[ot] = a;
    }

    // epilogue: +residual, write h
    float4 oo[4];
    #pragma unroll
    for (int ot = 0; ot < 4; ++ot) {
        int oc = ot * 16 + g * 4;
        float4 o;
        o.x = accO[ot][0]; o.y = accO[ot][1]; o.z = accO[ot][2]; o.w = accO[ot][3];
        if (valid) {
            if (hres) {
                float4 hr = *(const float4*)(hres + (size_t)node * HH + oc);
                o.x += hr.x; o.y += hr.y; o.z += hr.z; o.w += hr.w;
            }
            *(float4*)(hout + (size_t)node * HH + oc) = o;
        }
        oo[ot] = o;
    }
    if (!lng1) return;   // last layer: k_outg does the final LN (uniform exit)

    // next-layer LN(64)+ReLU, all in registers
    float s2 = 0.f, sq2 = 0.f;
    #pragma unroll
    for (int ot = 0; ot < 4; ++ot) {
        s2 += oo[ot].x + oo[ot].y + oo[ot].z + oo[ot].w;
        sq2 += oo[ot].x * oo[ot].x + oo[ot].y * oo[ot].y
             + oo[ot].z * oo[ot].z + oo[ot].w * oo[ot].w;
    }
    s2 += __shfl_xor(s2, 16); sq2 += __shfl_xor(sq2, 16);
    s2 += __shfl_xor(s2, 32); sq2 += __shfl_xor(sq2, 32);
    float mu2 = s2 * (1.f / 64.f);
    float var2 = sq2 * (1.f / 64.f) - mu2 * mu2;
    float rs2 = rsqrtf(fmaxf(var2, 0.f) + LNE);
    #pragma unroll
    for (int ot = 0; ot < 4; ++ot) {
        int oc = ot * 16 + g * 4;
        float4 gg = *(const float4*)(lng1 + oc);
        float4 bb = *(const float4*)(lnb1 + oc);
        float4 v;
        v.x = fmaxf((oo[ot].x - mu2) * rs2 * gg.x + bb.x, 0.f);
        v.y = fmaxf((oo[ot].y - mu2) * rs2 * gg.y + bb.y, 0.f);
        v.z = fmaxf((oo[ot].z - mu2) * rs2 * gg.z + bb.z, 0.f);
        v.w = fmaxf((oo[ot].w - mu2) * rs2 * gg.w + bb.w, 0.f);
        if (valid) {
            *(float4*)(y + (size_t)node * HH + oc) = v;
            ushort4 p;
            p.x = f2b(v.x); p.y = f2b(v.y); p.z = f2b(v.z); p.w = f2b(v.w);
            *(ushort4*)(ybf + (size_t)node * HH + oc) = p;
        }
    }
}

// ---------- MFMA final LN + both heads; g-head via dense per-block max (NO atomics) ----------
__global__ __launch_bounds__(256) void k_outg(const float* __restrict__ h,
                                              const float* __restrict__ lng, const float* __restrict__ lnb,
                                              const unsigned short* __restrict__ whh,
                                              const unsigned short* __restrict__ whl,
                                              const float* __restrict__ bc,
                                              float* __restrict__ dout, float* __restrict__ gmax) {
    __shared__ float smax[4][16];
    int tid = threadIdx.x;
    int w = tid >> 6, lane = tid & 63;
    int nl = lane & 15, g = lane >> 4;
    int node = blockIdx.x * 64 + w * 16 + nl;
    bool valid = node < NN;

    // load h chunks: k = kc*32 + g*8 + e
    float hv[16];
    if (valid) {
        const float* hp = h + (size_t)node * HH;
        float4 a0 = *(const float4*)(hp + g * 8);
        float4 a1 = *(const float4*)(hp + g * 8 + 4);
        float4 a2 = *(const float4*)(hp + 32 + g * 8);
        float4 a3 = *(const float4*)(hp + 32 + g * 8 + 4);
        hv[0] = a0.x; hv[1] = a0.y; hv[2] = a0.z; hv[3] = a0.w;
        hv[4] = a1.x; hv[5] = a1.y; hv[6] = a1.z; hv[7] = a1.w;
        hv[8] = a2.x; hv[9] = a2.y; hv[10] = a2.z; hv[11] = a2.w;
        hv[12] = a3.x; hv[13] = a3.y; hv[14] = a3.z; hv[15] = a3.w;
    } else {
        #pragma unroll
        for (int i = 0; i < 16; ++i) hv[i] = 0.f;
    }

    // LN(64) stats
    float s = 0.f, sq = 0.f;
    #pragma unroll
    for (int i = 0; i < 16; ++i) { s += hv[i]; sq += hv[i] * hv[i]; }
    s += __shfl_xor(s, 16); sq += __shfl_xor(sq, 16);
    s += __shfl_xor(s, 32); sq += __shfl_xor(sq, 32);
    float mu = s * (1.f / 64.f);
    float var = sq * (1.f / 64.f) - mu * mu;
    float rs = rsqrtf(fmaxf(var, 0.f) + LNE);

    // normalize + relu, pack bf16 hi/lo B-frags
    union { bf16x8 v; unsigned short u[8]; } Bh[2], Bl[2];
    #pragma unroll
    for (int kc = 0; kc < 2; ++kc) {
        int cb = kc * 32 + g * 8;
        float4 g0 = *(const float4*)(lng + cb);
        float4 g1 = *(const float4*)(lng + cb + 4);
        float4 b0 = *(const float4*)(lnb + cb);
        float4 b1v = *(const float4*)(lnb + cb + 4);
        float gv[8] = {g0.x, g0.y, g0.z, g0.w, g1.x, g1.y, g1.z, g1.w};
        float bv[8] = {b0.x, b0.y, b0.z, b0.w, b1v.x, b1v.y, b1v.z, b1v.w};
        #pragma unroll
        for (int e = 0; e < 8; ++e) {
            float v = fmaxf((hv[kc * 8 + e] - mu) * rs * gv[e] + bv[e], 0.f);
            unsigned short hi = f2b(v);
            Bh[kc].u[e] = hi;
            Bl[kc].u[e] = f2b(v - b2f(hi));
        }
    }

    // heads: 3 output tiles (j = t*16 + g*4 + reg), K=64, 3 MFMA per (t,kc)
    f32x4 acc[3];
    #pragma unroll
    for (int t = 0; t < 3; ++t) {
        int j0 = t * 16 + g * 4;
        float4 bb = *(const float4*)(bc + j0);
        f32x4 a = {bb.x, bb.y, bb.z, bb.w};
        #pragma unroll
        for (int kc = 0; kc < 2; ++kc) {
            size_t wo = (size_t)(t * 16 + nl) * 64 + kc * 32 + g * 8;
            bf16x8 ah = *(const bf16x8*)(whh + wo);
            bf16x8 al = *(const bf16x8*)(whl + wo);
            a = __builtin_amdgcn_mfma_f32_16x16x32_bf16(ah, Bh[kc].v, a, 0, 0, 0);
            a = __builtin_amdgcn_mfma_f32_16x16x32_bf16(al, Bh[kc].v, a, 0, 0, 0);
            a = __builtin_amdgcn_mfma_f32_16x16x32_bf16(ah, Bl[kc].v, a, 0, 0, 0);
        }
        acc[t] = a;
    }

    // n-head direct stores; g-head butterfly-max over node-lanes -> LDS -> block max
    #pragma unroll
    for (int t = 0; t < 3; ++t) {
        #pragma unroll
        for (int reg = 0; reg < 4; ++reg) {
            int j = t * 16 + g * 4 + reg;   // uniform within a g-group
            float val = acc[t][reg];
            if (j < ON) {
                if (valid) dout[OC + (size_t)node * ON + j] = val;
            } else if (j < 33) {
                float gv = valid ? val : -INFINITY;
                #pragma unroll
                for (int m = 1; m < 16; m <<= 1) gv = fmaxf(gv, __shfl_xor(gv, m));
                if (nl == 0) smax[w][j - ON] = gv;
            }
        }
    }
    __syncthreads();
    if (tid < 16) {
        float m = fmaxf(fmaxf(smax[0][tid], smax[1][tid]),
                        fmaxf(smax[2][tid], smax[3][tid]));
        gmax[(size_t)blockIdx.x * 16 + tid] = m;
    }
}

// 1-wave final reduce: gmax[NOB][16] -> dout[0..15]
__global__ void k_gdec(const float* __restrict__ gmax, float* __restrict__ dout) {
    int lane = threadIdx.x & 63;
    int ch = lane & 15, grp = lane >> 4;   // 4 groups stride over blocks
    float m = -INFINITY;
    for (int b = grp; b < NOB; b += 4) m = fmaxf(m, gmax[(size_t)b * 16 + ch]);
    m = fmaxf(m, __shfl_xor(m, 16));
    m = fmaxf(m, __shfl_xor(m, 32));
    if (lane < 16) dout[ch] = m;
}

// ---------- launch ----------
extern "C" void kernel_launch(void* const* d_in, const int* in_sizes, int n_in,
                              void* d_out, int out_size, void* d_ws, size_t ws_size,
                              hipStream_t stream) {
    const float* x     = (const float*)d_in[0];
    const float* nodeW = (const float*)d_in[1];
    const float* nodeB = (const float*)d_in[2];
    const float* W1    = (const float*)d_in[3];
    const float* b1    = (const float*)d_in[4];
    const float* mlg   = (const float*)d_in[5];
    const float* mlb   = (const float*)d_in[6];
    const float* W2    = (const float*)d_in[7];
    const float* b2    = (const float*)d_in[8];
    const float* tt    = (const float*)d_in[9];
    const float* lng   = (const float*)d_in[10];
    const float* lnb   = (const float*)d_in[11];
    const int*   ei    = (const int*)d_in[12];
    const float* gW    = (const float*)d_in[13];
    const float* gb    = (const float*)d_in[14];
    const float* nW    = (const float*)d_in[15];
    const float* nbp   = (const float*)d_in[16];
    float* out = (float*)d_out;

    char* ws = (char*)d_ws;
    size_t off = 0;
    auto alloc = [&](size_t bytes) -> void* {
        void* p = ws + off;
        off = (off + bytes + 255) & ~(size_t)255;
        return p;
    };
    int* counts    = (int*)alloc((size_t)NN * 4);
    size_t zero_end = off;
    float* gmax = (float*)alloc((size_t)NOB * 16 * 4);
    int* bsums = (int*)alloc(1024);
    int* rowst = (int*)alloc((size_t)NN * 4);
    int* ssrc  = (int*)alloc((size_t)NE * 4);
    float* h   = (float*)alloc((size_t)NN * HH * 4);
    float* y   = (float*)alloc((size_t)NN * HH * 4);
    unsigned short* agh = (unsigned short*)alloc((size_t)NN * HH * 2);
    unsigned short* agl = (unsigned short*)alloc((size_t)NN * HH * 2);
    unsigned short* ybf = (unsigned short*)alloc((size_t)NN * HH * 2);
    unsigned short* w1h = (unsigned short*)alloc((size_t)NL * H2 * HH * 2);
    unsigned short* w1l = (unsigned short*)alloc((size_t)NL * H2 * HH * 2);
    unsigned short* w2h = (unsigned short*)alloc((size_t)NL * H2 * HH * 2);
    unsigned short* w2l = (unsigned short*)alloc((size_t)NL * H2 * HH * 2);
    unsigned short* whh = (unsigned short*)alloc((size_t)48 * 64 * 2);
    unsigned short* whl = (unsigned short*)alloc((size_t)48 * 64 * 2);
    float* bc = (float*)alloc(48 * 4);
    int* rank = (int*)agh;   // alias: rank only lives during CSR build (3.2MB <= 6.4MB)

    const int* esrc = ei;
    const int* edst = ei + NE;

    hipMemsetAsync(d_ws, 0, zero_end, stream);

    k_wprep<<<(NL * H2 * HH + 255) / 256, 256, 0, stream>>>(W1, W2, nW, gW, nbp, gb,
                                                            w1h, w1l, w2h, w2l, whh, whl, bc);
    k_hist2<<<(NE + 255) / 256, 256, 0, stream>>>(edst, counts, rank);
    k_scan1<<<SCAN_BLOCKS, 256, 0, stream>>>(counts, rowst, bsums);
    k_scan2<<<1, 256, 0, stream>>>(bsums);
    k_scan3<<<SCAN_BLOCKS, 256, 0, stream>>>(counts, rowst, bsums);
    k_scatter2<<<(NE + 255) / 256, 256, 0, stream>>>(esrc, edst, rank, rowst, ssrc);
    k_encoder<<<(NN + 3) / 4, 256, 0, stream>>>(x, nodeW, nodeB, h, ybf);

    for (int l = 0; l < NL; ++l) {
        const float* yin = (l == 0) ? h : y;
        k_agg<<<(NN + 3) / 4, 256, 0, stream>>>(yin, ybf, rowst, counts, ssrc, tt + l, agh, agl);
        const float* ln1g = (l < NL - 1) ? (lng + (size_t)(l + 1) * HH) : nullptr;
        const float* ln1b = (l < NL - 1) ? (lnb + (size_t)(l + 1) * HH) : nullptr;
        k_mlp<<<(NN + 63) / 64, 256, 0, stream>>>(agh, agl,
                                                  w1h + (size_t)l * H2 * HH, w1l + (size_t)l * H2 * HH,
                                                  b1 + (size_t)l * H2,
                                                  mlg + (size_t)l * H2, mlb + (size_t)l * H2,
                                                  w2h + (size_t)l * H2 * HH, w2l + (size_t)l * H2 * HH,
                                                  b2 + (size_t)l * HH,
                                                  (l == 0) ? (const float*)nullptr : h, h,
                                                  ln1g, ln1b, y, ybf);
    }
    k_outg<<<NOB, 256, 0, stream>>>(h, lng, lnb, whh, whl, bc, out, gmax);
    k_gdec<<<1, 64, 0, stream>>>(gmax, out);
}

// Round 10
// 407.315 us; speedup vs baseline: 1.6112x; 1.0263x over previous
//
#include <hip/hip_runtime.h>

#define NN 50000
#define NE 800000
#define INC 32
#define HH 64
#define H2 128
#define OC 16
#define ON 17
#define NL 4
#define MEPS 1e-7f
#define LNE 1e-5f
#define SCAN_BLOCKS 196   /* ceil(50000/256) */
#define NOB ((NN + 63) / 64)   /* k_outg blocks = 782 */

typedef __attribute__((ext_vector_type(8))) short bf16x8;
typedef __attribute__((ext_vector_type(4))) float f32x4;

// ---------- bf16 helpers (RNE) ----------
__device__ __forceinline__ unsigned short f2b(float x) {
    unsigned b = __float_as_uint(x);
    b += 0x7FFFu + ((b >> 16) & 1u);
    return (unsigned short)(b >> 16);
}
__device__ __forceinline__ float b2f(unsigned short u) {
    return __uint_as_float(((unsigned)u) << 16);
}

// ---------- CSR build ----------
__global__ __launch_bounds__(256) void k_hist2(const int* __restrict__ dst, int* __restrict__ counts,
                                               int* __restrict__ rank) {
    int e = blockIdx.x * 256 + threadIdx.x;
    if (e < NE) rank[e] = atomicAdd(&counts[dst[e]], 1);
}

__global__ __launch_bounds__(256) void k_scan1(const int* __restrict__ counts,
                                               int* __restrict__ incl, int* __restrict__ bsums) {
    __shared__ int s[256];
    int t = threadIdx.x;
    int i = blockIdx.x * 256 + t;
    int v = (i < NN) ? counts[i] : 0;
    s[t] = v;
    __syncthreads();
    for (int off = 1; off < 256; off <<= 1) {
        int x = (t >= off) ? s[t - off] : 0;
        __syncthreads();
        s[t] += x;
        __syncthreads();
    }
    if (i < NN) incl[i] = s[t];
    if (t == 255) bsums[blockIdx.x] = s[255];
}

__global__ __launch_bounds__(256) void k_scan2(int* __restrict__ bsums) {
    __shared__ int s[256];
    int t = threadIdx.x;
    int v = (t < SCAN_BLOCKS) ? bsums[t] : 0;
    s[t] = v;
    __syncthreads();
    for (int off = 1; off < 256; off <<= 1) {
        int x = (t >= off) ? s[t - off] : 0;
        __syncthreads();
        s[t] += x;
        __syncthreads();
    }
    if (t < SCAN_BLOCKS) bsums[t] = s[t] - v;  // exclusive
}

// scan3 also emits meta[n] = (start, deg) so k_agg has one dependent load, not two.
__global__ __launch_bounds__(256) void k_scan3(const int* __restrict__ counts,
                                               int* __restrict__ rowst, const int* __restrict__ bsums,
                                               int2* __restrict__ meta) {
    int i = blockIdx.x * 256 + threadIdx.x;
    if (i < NN) {
        int st = rowst[i] - counts[i] + bsums[blockIdx.x];
        rowst[i] = st;
        meta[i] = make_int2(st, counts[i]);
    }
}

__global__ __launch_bounds__(256) void k_scatter2(const int* __restrict__ src, const int* __restrict__ dst,
                                                  const int* __restrict__ rank, const int* __restrict__ rowst,
                                                  int* __restrict__ ssrc) {
    int e = blockIdx.x * 256 + threadIdx.x;
    if (e < NE) ssrc[rowst[dst[e]] + rank[e]] = src[e];
}

// ---------- weight prep (one-time): transpose + bf16 hi/lo split ----------
__global__ __launch_bounds__(256) void k_wprep(const float* __restrict__ W1, const float* __restrict__ W2,
                                               const float* __restrict__ nW, const float* __restrict__ gW,
                                               const float* __restrict__ nbp, const float* __restrict__ gb,
                                               unsigned short* __restrict__ w1h, unsigned short* __restrict__ w1l,
                                               unsigned short* __restrict__ w2h, unsigned short* __restrict__ w2l,
                                               unsigned short* __restrict__ whh, unsigned short* __restrict__ whl,
                                               float* __restrict__ bc) {
    int i = blockIdx.x * 256 + threadIdx.x;
    if (i < 48 * 64) {
        int j = i >> 6, k = i & 63;
        float v = 0.f;
        if (j < ON) v = nW[k * ON + j];
        else if (j < 33) v = gW[k * OC + (j - ON)];
        unsigned short hi = f2b(v);
        whh[i] = hi;
        whl[i] = f2b(v - b2f(hi));
    }
    if (i < 48) bc[i] = (i < ON) ? nbp[i] : ((i < 33) ? gb[i - ON] : 0.f);
    if (i >= NL * H2 * HH) return;
    int l = i / (H2 * HH), r = i % (H2 * HH);
    {
        int c = r / HH, k = r % HH;
        float v = W1[(size_t)l * HH * H2 + (size_t)k * H2 + c];
        unsigned short hi = f2b(v);
        w1h[i] = hi;
        w1l[i] = f2b(v - b2f(hi));
    }
    {
        int c = r / H2, k = r % H2;
        float v = W2[(size_t)l * H2 * HH + (size_t)k * HH + c];
        unsigned short hi = f2b(v);
        w2h[i] = hi;
        w2l[i] = f2b(v - b2f(hi));
    }
}

// ---------- node encoder: h = x @ W + b  ([N,32]@[32,64]), also bf16 shadow ----------
__global__ __launch_bounds__(256) void k_encoder(const float* __restrict__ x, const float* __restrict__ W,
                                                 const float* __restrict__ b, float* __restrict__ h,
                                                 unsigned short* __restrict__ hbf) {
    __shared__ float Ws[INC * HH];
    __shared__ float bs[HH];
    int tid = threadIdx.x;
    for (int i = tid; i < INC * HH; i += 256) Ws[i] = W[i];
    if (tid < HH) bs[tid] = b[tid];
    __syncthreads();
    int wid = tid >> 6, lane = tid & 63;
    int n = blockIdx.x * 4 + wid;
    if (n >= NN) return;
    float v = (lane < INC) ? x[(size_t)n * INC + lane] : 0.f;
    float acc = bs[lane];
    #pragma unroll
    for (int k = 0; k < INC; ++k)
        acc += __shfl(v, k) * Ws[k * HH + lane];
    h[(size_t)n * HH + lane] = acc;
    hbf[(size_t)n * HH + lane] = f2b(acc);
}

// ---------- per-dst softmax aggregation: HALF-WAVE per node ----------
// Round-9 redesign: lane = channel-pair of its half's node -> per-channel softmax
// accumulates entirely in-lane (NO cross-lane reduction), 2 nodes/wave (half the
// waves), meta=int2 (one dependent load). Loop bounds are wave-uniform (max of the
// two nodes' windows) so every __shfl executes fully converged.
__global__ __launch_bounds__(256) void k_agg(const float* __restrict__ y,
                                             const unsigned short* __restrict__ ybf,
                                             const int2* __restrict__ meta,
                                             const int* __restrict__ ssrc,
                                             const float* __restrict__ tp,
                                             unsigned short* __restrict__ agh,
                                             unsigned short* __restrict__ agl) {
    int tid = threadIdx.x;
    int w = tid >> 6, lane = tid & 63;
    int half = lane >> 5;          // 0 -> node A, 1 -> node B
    int l = lane & 31;             // index within half
    int col = l;                   // channel-pair (channels 2col, 2col+1)
    int n = blockIdx.x * 8 + w * 2 + half;
    bool valid = n < NN;
    float tval = *tp;
    int2 m = valid ? meta[n] : make_int2(0, 0);
    int start = m.x, deg = m.y;

    // wave-uniform max degree of the two nodes (deg is uniform within each half)
    int dA = __shfl(deg, 0), dB = __shfl(deg, 32);
    int dmax = max(dA, dB);

    float Sa0 = 0.f, Sm0 = 0.f, Sa1 = 0.f, Sm1 = 0.f;
    for (int win = 0; win < dmax; win += 64) {
        int rem = dmax - win;                       // uniform
        int wcnt = min(64, rem);                    // uniform inner bound
        // per-half index registers for this 64-edge window
        int idxLo = (win + l < deg) ? ssrc[start + win + l] : 0;
        int idxHi = (win + 32 + l < deg) ? ssrc[start + win + 32 + l] : 0;
        for (int e0 = 0; e0 < wcnt; e0 += 8) {
            float c0[8], c1[8];
            int ev[8];
            #pragma unroll
            for (int i = 0; i < 8; ++i) {
                int e = e0 + i;                     // uniform
                ev[i] = win + e;
                int sel = (e < 32) ? idxLo : idxHi;
                int s = __shfl(sel, (lane & 32) | (e & 31));
                unsigned v = *(const unsigned*)(ybf + (size_t)s * HH + col * 2);
                c0[i] = b2f((unsigned short)(v & 0xffffu));
                c1[i] = b2f((unsigned short)(v >> 16));
            }
            #pragma unroll
            for (int i = 0; i < 8; ++i) {
                bool ok = ev[i] < deg;              // uniform per half
                float m0 = fmaxf(c0[i], 0.f) + MEPS;
                float m1 = fmaxf(c1[i], 0.f) + MEPS;
                float a0 = ok ? __expf(tval * m0) : 0.f;
                float a1 = ok ? __expf(tval * m1) : 0.f;
                Sa0 += a0; Sm0 += m0 * a0;
                Sa1 += a1; Sm1 += m1 * a1;
            }
        }
    }
    if (!valid) return;
    float agg0 = Sm0 / fmaxf(Sa0, MEPS);            // deg==0 -> 0
    float agg1 = Sm1 / fmaxf(Sa1, MEPS);
    float2 yv = *(const float2*)(y + (size_t)n * HH + col * 2);
    float av0 = agg0 + yv.x;
    float av1 = agg1 + yv.y;
    unsigned short h0 = f2b(av0), h1 = f2b(av1);
    ushort2 ph = {h0, h1};
    ushort2 pl = {f2b(av0 - b2f(h0)), f2b(av1 - b2f(h1))};
    *(ushort2*)(agh + (size_t)n * HH + col * 2) = ph;
    *(ushort2*)(agl + (size_t)n * HH + col * 2) = pl;
}

// ---------- MFMA fused MLP with LDS-staged weights ----------
// Round-7 lesson: per-wave fragment loads from L2 serialize. Fix: block-cooperative
// coalesced staging of W1/W2 hi+lo into LDS (70KB, 2 blocks/CU); fragment reads are
// ds_read_b128. Ut aliases W1hi space after gemmA (one barrier).
__global__ __launch_bounds__(256) void k_mlp(
    const unsigned short* __restrict__ agh, const unsigned short* __restrict__ agl,
    const unsigned short* __restrict__ w1h, const unsigned short* __restrict__ w1l,
    const float* __restrict__ b1,
    const float* __restrict__ mlg, const float* __restrict__ mlb,
    const unsigned short* __restrict__ w2h, const unsigned short* __restrict__ w2l,
    const float* __restrict__ b2,
    const float* __restrict__ hres, float* __restrict__ hout,
    const float* __restrict__ lng1, const float* __restrict__ lnb1,
    float* __restrict__ y, unsigned short* __restrict__ ybf)
{
    __shared__ __align__(16) unsigned short W1hS[128 * 72];   // 18432B; Ut aliases here later
    __shared__ __align__(16) unsigned short W1lS[128 * 72];
    __shared__ __align__(16) unsigned short W2hS[64 * 136];   // 17408B
    __shared__ __align__(16) unsigned short W2lS[64 * 136];
    int tid = threadIdx.x;
    int w = tid >> 6, lane = tid & 63;
    int nl = lane & 15, g = lane >> 4;
    int node = blockIdx.x * 64 + w * 16 + nl;
    bool valid = node < NN;

    // ---- issue ag loads FIRST (HBM latency hides under weight staging)
    bf16x8 bAh[2], bAl[2];
    {
        bf16x8 z = {0, 0, 0, 0, 0, 0, 0, 0};
        if (valid) {
            const unsigned short* rp = agh + (size_t)node * HH + g * 8;
            bAh[0] = *(const bf16x8*)rp;
            bAh[1] = *(const bf16x8*)(rp + 32);
            const unsigned short* rq = agl + (size_t)node * HH + g * 8;
            bAl[0] = *(const bf16x8*)rq;
            bAl[1] = *(const bf16x8*)(rq + 32);
        } else {
            bAh[0] = z; bAh[1] = z; bAl[0] = z; bAl[1] = z;
        }
    }

    // ---- cooperative weight staging: 16 coalesced 16B loads/thread
    #pragma unroll
    for (int it = 0; it < 4; ++it) {                 // W1: 1024 chunks, row=c>>3
        int c = tid + it * 256;
        int row = c >> 3, col = (c & 7) << 3;
        float4 vh = *(const float4*)(w1h + c * 8);
        float4 vl = *(const float4*)(w1l + c * 8);
        *(float4*)&W1hS[row * 72 + col] = vh;
        *(float4*)&W1lS[row * 72 + col] = vl;
    }
    #pragma unroll
    for (int it = 0; it < 4; ++it) {                 // W2: 1024 chunks, row=c>>4
        int c = tid + it * 256;
        int row = c >> 4, col = (c & 15) << 3;
        float4 vh = *(const float4*)(w2h + c * 8);
        float4 vl = *(const float4*)(w2l + c * 8);
        *(float4*)&W2hS[row * 136 + col] = vh;
        *(float4*)&W2lS[row * 136 + col] = vl;
    }
    __syncthreads();

    // ---- gemmA: U^T tiles (8 x 16 ucols), K=64. 3 MFMA per (t,kc), frags from LDS
    f32x4 accU[8];
    #pragma unroll
    for (int t = 0; t < 8; ++t) {
        int uc = t * 16 + g * 4;
        float4 bb = *(const float4*)(b1 + uc);
        f32x4 a = {bb.x, bb.y, bb.z, bb.w};
        #pragma unroll
        for (int kc = 0; kc < 2; ++kc) {
            int wo = (t * 16 + nl) * 72 + kc * 32 + g * 8;
            bf16x8 ah = *(const bf16x8*)&W1hS[wo];
            bf16x8 al = *(const bf16x8*)&W1lS[wo];
            a = __builtin_amdgcn_mfma_f32_16x16x32_bf16(ah, bAh[kc], a, 0, 0, 0);
            a = __builtin_amdgcn_mfma_f32_16x16x32_bf16(al, bAh[kc], a, 0, 0, 0);
            a = __builtin_amdgcn_mfma_f32_16x16x32_bf16(ah, bAl[kc], a, 0, 0, 0);
        }
        accU[t] = a;
    }

    // ---- LN(128): node = lane&15 -> in-lane + 2 shfl_xor
    float s = 0.f, sq = 0.f;
    #pragma unroll
    for (int t = 0; t < 8; ++t) {
        #pragma unroll
        for (int j = 0; j < 4; ++j) { float v = accU[t][j]; s += v; sq += v * v; }
    }
    s += __shfl_xor(s, 16); sq += __shfl_xor(sq, 16);
    s += __shfl_xor(s, 32); sq += __shfl_xor(sq, 32);
    float mu = s * (1.f / 128.f);
    float var = sq * (1.f / 128.f) - mu * mu;
    float rs = rsqrtf(fmaxf(var, 0.f) + LNE);

    __syncthreads();   // all waves done reading W1 LDS -> Ut may overwrite it
    unsigned short* myUt = W1hS + w * (16 * 136);   // 4352B/wave, 16B-aligned

    // normalize + relu + pack bf16 -> myUt[node][ucol]
    #pragma unroll
    for (int t = 0; t < 8; ++t) {
        int uc = t * 16 + g * 4;
        float4 gg = *(const float4*)(mlg + uc);
        float4 bb = *(const float4*)(mlb + uc);
        ushort4 pk;
        pk.x = f2b(fmaxf((accU[t][0] - mu) * rs * gg.x + bb.x, 0.f));
        pk.y = f2b(fmaxf((accU[t][1] - mu) * rs * gg.y + bb.y, 0.f));
        pk.z = f2b(fmaxf((accU[t][2] - mu) * rs * gg.z + bb.z, 0.f));
        pk.w = f2b(fmaxf((accU[t][3] - mu) * rs * gg.w + bb.w, 0.f));
        *(ushort4*)(&myUt[nl * 136 + uc]) = pk;
    }
    // per-wave slice: only our own wave's writes must land before our reads
    asm volatile("s_waitcnt lgkmcnt(0)" ::: "memory");

    // B-frags for gemmB: P^T
    bf16x8 bB[4];
    #pragma unroll
    for (int kc = 0; kc < 4; ++kc)
        bB[kc] = *(const bf16x8*)(&myUt[nl * 136 + kc * 32 + g * 8]);

    // gemmB: O^T tiles (4 x 16 ocols), K=128. 2 MFMA per (ot,kc), frags from LDS
    f32x4 accO[4];
    #pragma unroll
    for (int ot = 0; ot < 4; ++ot) {
        int oc = ot * 16 + g * 4;
        float4 bb = *(const float4*)(b2 + oc);
        f32x4 a = {bb.x, bb.y, bb.z, bb.w};
        #pragma unroll
        for (int kc = 0; kc < 4; ++kc) {
            int wo = (ot * 16 + nl) * 136 + kc * 32 + g * 8;
            bf16x8 ah = *(const bf16x8*)&W2hS[wo];
            bf16x8 al = *(const bf16x8*)&W2lS[wo];
            a = __builtin_amdgcn_mfma_f32_16x16x32_bf16(ah, bB[kc], a, 0, 0, 0);
            a = __builtin_amdgcn_mfma_f32_16x16x32_bf16(al, bB[kc], a, 0, 0, 0);
        }
        accO[ot] = a;
    }

    // epilogue: +residual, write h
    float4 oo[4];
    #pragma unroll
    for (int ot = 0; ot < 4; ++ot) {
        int oc = ot * 16 + g * 4;
        float4 o;
        o.x = accO[ot][0]; o.y = accO[ot][1]; o.z = accO[ot][2]; o.w = accO[ot][3];
        if (valid) {
            if (hres) {
                float4 hr = *(const float4*)(hres + (size_t)node * HH + oc);
                o.x += hr.x; o.y += hr.y; o.z += hr.z; o.w += hr.w;
            }
            *(float4*)(hout + (size_t)node * HH + oc) = o;
        }
        oo[ot] = o;
    }
    if (!lng1) return;   // last layer: k_outg does the final LN (uniform exit)

    // next-layer LN(64)+ReLU, all in registers
    float s2 = 0.f, sq2 = 0.f;
    #pragma unroll
    for (int ot = 0; ot < 4; ++ot) {
        s2 += oo[ot].x + oo[ot].y + oo[ot].z + oo[ot].w;
        sq2 += oo[ot].x * oo[ot].x + oo[ot].y * oo[ot].y
             + oo[ot].z * oo[ot].z + oo[ot].w * oo[ot].w;
    }
    s2 += __shfl_xor(s2, 16); sq2 += __shfl_xor(sq2, 16);
    s2 += __shfl_xor(s2, 32); sq2 += __shfl_xor(sq2, 32);
    float mu2 = s2 * (1.f / 64.f);
    float var2 = sq2 * (1.f / 64.f) - mu2 * mu2;
    float rs2 = rsqrtf(fmaxf(var2, 0.f) + LNE);
    #pragma unroll
    for (int ot = 0; ot < 4; ++ot) {
        int oc = ot * 16 + g * 4;
        float4 gg = *(const float4*)(lng1 + oc);
        float4 bb = *(const float4*)(lnb1 + oc);
        float4 v;
        v.x = fmaxf((oo[ot].x - mu2) * rs2 * gg.x + bb.x, 0.f);
        v.y = fmaxf((oo[ot].y - mu2) * rs2 * gg.y + bb.y, 0.f);
        v.z = fmaxf((oo[ot].z - mu2) * rs2 * gg.z + bb.z, 0.f);
        v.w = fmaxf((oo[ot].w - mu2) * rs2 * gg.w + bb.w, 0.f);
        if (valid) {
            *(float4*)(y + (size_t)node * HH + oc) = v;
            ushort4 p;
            p.x = f2b(v.x); p.y = f2b(v.y); p.z = f2b(v.z); p.w = f2b(v.w);
            *(ushort4*)(ybf + (size_t)node * HH + oc) = p;
        }
    }
}

// ---------- MFMA final LN + both heads; g-head via dense per-block max (NO atomics) ----------
__global__ __launch_bounds__(256) void k_outg(const float* __restrict__ h,
                                              const float* __restrict__ lng, const float* __restrict__ lnb,
                                              const unsigned short* __restrict__ whh,
                                              const unsigned short* __restrict__ whl,
                                              const float* __restrict__ bc,
                                              float* __restrict__ dout, float* __restrict__ gmax) {
    __shared__ float smax[4][16];
    int tid = threadIdx.x;
    int w = tid >> 6, lane = tid & 63;
    int nl = lane & 15, g = lane >> 4;
    int node = blockIdx.x * 64 + w * 16 + nl;
    bool valid = node < NN;

    // load h chunks: k = kc*32 + g*8 + e
    float hv[16];
    if (valid) {
        const float* hp = h + (size_t)node * HH;
        float4 a0 = *(const float4*)(hp + g * 8);
        float4 a1 = *(const float4*)(hp + g * 8 + 4);
        float4 a2 = *(const float4*)(hp + 32 + g * 8);
        float4 a3 = *(const float4*)(hp + 32 + g * 8 + 4);
        hv[0] = a0.x; hv[1] = a0.y; hv[2] = a0.z; hv[3] = a0.w;
        hv[4] = a1.x; hv[5] = a1.y; hv[6] = a1.z; hv[7] = a1.w;
        hv[8] = a2.x; hv[9] = a2.y; hv[10] = a2.z; hv[11] = a2.w;
        hv[12] = a3.x; hv[13] = a3.y; hv[14] = a3.z; hv[15] = a3.w;
    } else {
        #pragma unroll
        for (int i = 0; i < 16; ++i) hv[i] = 0.f;
    }

    // LN(64) stats
    float s = 0.f, sq = 0.f;
    #pragma unroll
    for (int i = 0; i < 16; ++i) { s += hv[i]; sq += hv[i] * hv[i]; }
    s += __shfl_xor(s, 16); sq += __shfl_xor(sq, 16);
    s += __shfl_xor(s, 32); sq += __shfl_xor(sq, 32);
    float mu = s * (1.f / 64.f);
    float var = sq * (1.f / 64.f) - mu * mu;
    float rs = rsqrtf(fmaxf(var, 0.f) + LNE);

    // normalize + relu, pack bf16 hi/lo B-frags
    union { bf16x8 v; unsigned short u[8]; } Bh[2], Bl[2];
    #pragma unroll
    for (int kc = 0; kc < 2; ++kc) {
        int cb = kc * 32 + g * 8;
        float4 g0 = *(const float4*)(lng + cb);
        float4 g1 = *(const float4*)(lng + cb + 4);
        float4 b0 = *(const float4*)(lnb + cb);
        float4 b1v = *(const float4*)(lnb + cb + 4);
        float gv[8] = {g0.x, g0.y, g0.z, g0.w, g1.x, g1.y, g1.z, g1.w};
        float bv[8] = {b0.x, b0.y, b0.z, b0.w, b1v.x, b1v.y, b1v.z, b1v.w};
        #pragma unroll
        for (int e = 0; e < 8; ++e) {
            float v = fmaxf((hv[kc * 8 + e] - mu) * rs * gv[e] + bv[e], 0.f);
            unsigned short hi = f2b(v);
            Bh[kc].u[e] = hi;
            Bl[kc].u[e] = f2b(v - b2f(hi));
        }
    }

    // heads: 3 output tiles (j = t*16 + g*4 + reg), K=64, 3 MFMA per (t,kc)
    f32x4 acc[3];
    #pragma unroll
    for (int t = 0; t < 3; ++t) {
        int j0 = t * 16 + g * 4;
        float4 bb = *(const float4*)(bc + j0);
        f32x4 a = {bb.x, bb.y, bb.z, bb.w};
        #pragma unroll
        for (int kc = 0; kc < 2; ++kc) {
            size_t wo = (size_t)(t * 16 + nl) * 64 + kc * 32 + g * 8;
            bf16x8 ah = *(const bf16x8*)(whh + wo);
            bf16x8 al = *(const bf16x8*)(whl + wo);
            a = __builtin_amdgcn_mfma_f32_16x16x32_bf16(ah, Bh[kc].v, a, 0, 0, 0);
            a = __builtin_amdgcn_mfma_f32_16x16x32_bf16(al, Bh[kc].v, a, 0, 0, 0);
            a = __builtin_amdgcn_mfma_f32_16x16x32_bf16(ah, Bl[kc].v, a, 0, 0, 0);
        }
        acc[t] = a;
    }

    // n-head direct stores; g-head butterfly-max over node-lanes -> LDS -> block max
    #pragma unroll
    for (int t = 0; t < 3; ++t) {
        #pragma unroll
        for (int reg = 0; reg < 4; ++reg) {
            int j = t * 16 + g * 4 + reg;   // uniform within a g-group
            float val = acc[t][reg];
            if (j < ON) {
                if (valid) dout[OC + (size_t)node * ON + j] = val;
            } else if (j < 33) {
                float gv = valid ? val : -INFINITY;
                #pragma unroll
                for (int m = 1; m < 16; m <<= 1) gv = fmaxf(gv, __shfl_xor(gv, m));
                if (nl == 0) smax[w][j - ON] = gv;
            }
        }
    }
    __syncthreads();
    if (tid < 16) {
        float m = fmaxf(fmaxf(smax[0][tid], smax[1][tid]),
                        fmaxf(smax[2][tid], smax[3][tid]));
        gmax[(size_t)blockIdx.x * 16 + tid] = m;
    }
}

// 1-wave final reduce: gmax[NOB][16] -> dout[0..15]
__global__ void k_gdec(const float* __restrict__ gmax, float* __restrict__ dout) {
    int lane = threadIdx.x & 63;
    int ch = lane & 15, grp = lane >> 4;   // 4 groups stride over blocks
    float m = -INFINITY;
    for (int b = grp; b < NOB; b += 4) m = fmaxf(m, gmax[(size_t)b * 16 + ch]);
    m = fmaxf(m, __shfl_xor(m, 16));
    m = fmaxf(m, __shfl_xor(m, 32));
    if (lane < 16) dout[ch] = m;
}

// ---------- launch ----------
extern "C" void kernel_launch(void* const* d_in, const int* in_sizes, int n_in,
                              void* d_out, int out_size, void* d_ws, size_t ws_size,
                              hipStream_t stream) {
    const float* x     = (const float*)d_in[0];
    const float* nodeW = (const float*)d_in[1];
    const float* nodeB = (const float*)d_in[2];
    const float* W1    = (const float*)d_in[3];
    const float* b1    = (const float*)d_in[4];
    const float* mlg   = (const float*)d_in[5];
    const float* mlb   = (const float*)d_in[6];
    const float* W2    = (const float*)d_in[7];
    const float* b2    = (const float*)d_in[8];
    const float* tt    = (const float*)d_in[9];
    const float* lng   = (const float*)d_in[10];
    const float* lnb   = (const float*)d_in[11];
    const int*   ei    = (const int*)d_in[12];
    const float* gW    = (const float*)d_in[13];
    const float* gb    = (const float*)d_in[14];
    const float* nW    = (const float*)d_in[15];
    const float* nbp   = (const float*)d_in[16];
    float* out = (float*)d_out;

    char* ws = (char*)d_ws;
    size_t off = 0;
    auto alloc = [&](size_t bytes) -> void* {
        void* p = ws + off;
        off = (off + bytes + 255) & ~(size_t)255;
        return p;
    };
    int* counts    = (int*)alloc((size_t)NN * 4);
    size_t zero_end = off;
    float* gmax = (float*)alloc((size_t)NOB * 16 * 4);
    int* bsums = (int*)alloc(1024);
    int* rowst = (int*)alloc((size_t)NN * 4);
    int2* meta = (int2*)alloc((size_t)NN * 8);
    int* ssrc  = (int*)alloc((size_t)NE * 4);
    float* h   = (float*)alloc((size_t)NN * HH * 4);
    float* y   = (float*)alloc((size_t)NN * HH * 4);
    unsigned short* agh = (unsigned short*)alloc((size_t)NN * HH * 2);
    unsigned short* agl = (unsigned short*)alloc((size_t)NN * HH * 2);
    unsigned short* ybf = (unsigned short*)alloc((size_t)NN * HH * 2);
    unsigned short* w1h = (unsigned short*)alloc((size_t)NL * H2 * HH * 2);
    unsigned short* w1l = (unsigned short*)alloc((size_t)NL * H2 * HH * 2);
    unsigned short* w2h = (unsigned short*)alloc((size_t)NL * H2 * HH * 2);
    unsigned short* w2l = (unsigned short*)alloc((size_t)NL * H2 * HH * 2);
    unsigned short* whh = (unsigned short*)alloc((size_t)48 * 64 * 2);
    unsigned short* whl = (unsigned short*)alloc((size_t)48 * 64 * 2);
    float* bc = (float*)alloc(48 * 4);
    int* rank = (int*)agh;   // alias: rank only lives during CSR build (3.2MB <= 6.4MB)

    const int* esrc = ei;
    const int* edst = ei + NE;

    hipMemsetAsync(d_ws, 0, zero_end, stream);

    k_wprep<<<(NL * H2 * HH + 255) / 256, 256, 0, stream>>>(W1, W2, nW, gW, nbp, gb,
                                                            w1h, w1l, w2h, w2l, whh, whl, bc);
    k_hist2<<<(NE + 255) / 256, 256, 0, stream>>>(edst, counts, rank);
    k_scan1<<<SCAN_BLOCKS, 256, 0, stream>>>(counts, rowst, bsums);
    k_scan2<<<1, 256, 0, stream>>>(bsums);
    k_scan3<<<SCAN_BLOCKS, 256, 0, stream>>>(counts, rowst, bsums, meta);
    k_scatter2<<<(NE + 255) / 256, 256, 0, stream>>>(esrc, edst, rank, rowst, ssrc);
    k_encoder<<<(NN + 3) / 4, 256, 0, stream>>>(x, nodeW, nodeB, h, ybf);

    for (int l = 0; l < NL; ++l) {
        const float* yin = (l == 0) ? h : y;
        k_agg<<<(NN + 7) / 8, 256, 0, stream>>>(yin, ybf, meta, ssrc, tt + l, agh, agl);
        const float* ln1g = (l < NL - 1) ? (lng + (size_t)(l + 1) * HH) : nullptr;
        const float* ln1b = (l < NL - 1) ? (lnb + (size_t)(l + 1) * HH) : nullptr;
        k_mlp<<<(NN + 63) / 64, 256, 0, stream>>>(agh, agl,
                                                  w1h + (size_t)l * H2 * HH, w1l + (size_t)l * H2 * HH,
                                                  b1 + (size_t)l * H2,
                                                  mlg + (size_t)l * H2, mlb + (size_t)l * H2,
                                                  w2h + (size_t)l * H2 * HH, w2l + (size_t)l * H2 * HH,
                                                  b2 + (size_t)l * HH,
                                                  (l == 0) ? (const float*)nullptr : h, h,
                                                  ln1g, ln1b, y, ybf);
    }
    k_outg<<<NOB, 256, 0, stream>>>(h, lng, lnb, whh, whl, bc, out, gmax);
    k_gdec<<<1, 64, 0, stream>>>(gmax, out);
}

// Round 11
// 402.354 us; speedup vs baseline: 1.6311x; 1.0123x over previous
//
#include <hip/hip_runtime.h>

#define NN 50000
#define NE 800000
#define INC 32
#define HH 64
#define H2 128
#define OC 16
#define ON 17
#define NL 4
#define MEPS 1e-7f
#define LNE 1e-5f
#define SCAN_BLOCKS 196   /* ceil(50000/256) */
#define NOB ((NN + 63) / 64)   /* k_outg blocks = 782 */

typedef __attribute__((ext_vector_type(8))) short bf16x8;
typedef __attribute__((ext_vector_type(4))) float f32x4;

// ---------- bf16 helpers (RNE) ----------
__device__ __forceinline__ unsigned short f2b(float x) {
    unsigned b = __float_as_uint(x);
    b += 0x7FFFu + ((b >> 16) & 1u);
    return (unsigned short)(b >> 16);
}
__device__ __forceinline__ float b2f(unsigned short u) {
    return __uint_as_float(((unsigned)u) << 16);
}

// ---------- CSR build ----------
__global__ __launch_bounds__(256) void k_hist2(const int* __restrict__ dst, int* __restrict__ counts,
                                               int* __restrict__ rank) {
    int e = blockIdx.x * 256 + threadIdx.x;
    if (e < NE) rank[e] = atomicAdd(&counts[dst[e]], 1);
}

__global__ __launch_bounds__(256) void k_scan1(const int* __restrict__ counts,
                                               int* __restrict__ incl, int* __restrict__ bsums) {
    __shared__ int s[256];
    int t = threadIdx.x;
    int i = blockIdx.x * 256 + t;
    int v = (i < NN) ? counts[i] : 0;
    s[t] = v;
    __syncthreads();
    for (int off = 1; off < 256; off <<= 1) {
        int x = (t >= off) ? s[t - off] : 0;
        __syncthreads();
        s[t] += x;
        __syncthreads();
    }
    if (i < NN) incl[i] = s[t];
    if (t == 255) bsums[blockIdx.x] = s[255];
}

__global__ __launch_bounds__(256) void k_scan2(int* __restrict__ bsums) {
    __shared__ int s[256];
    int t = threadIdx.x;
    int v = (t < SCAN_BLOCKS) ? bsums[t] : 0;
    s[t] = v;
    __syncthreads();
    for (int off = 1; off < 256; off <<= 1) {
        int x = (t >= off) ? s[t - off] : 0;
        __syncthreads();
        s[t] += x;
        __syncthreads();
    }
    if (t < SCAN_BLOCKS) bsums[t] = s[t] - v;  // exclusive
}

// scan3 also emits meta[n] = (start, deg) so k_agg has one dependent load, not two.
__global__ __launch_bounds__(256) void k_scan3(const int* __restrict__ counts,
                                               int* __restrict__ rowst, const int* __restrict__ bsums,
                                               int2* __restrict__ meta) {
    int i = blockIdx.x * 256 + threadIdx.x;
    if (i < NN) {
        int st = rowst[i] - counts[i] + bsums[blockIdx.x];
        rowst[i] = st;
        meta[i] = make_int2(st, counts[i]);
    }
}

__global__ __launch_bounds__(256) void k_scatter2(const int* __restrict__ src, const int* __restrict__ dst,
                                                  const int* __restrict__ rank, const int* __restrict__ rowst,
                                                  int* __restrict__ ssrc) {
    int e = blockIdx.x * 256 + threadIdx.x;
    if (e < NE) ssrc[rowst[dst[e]] + rank[e]] = src[e];
}

// ---------- weight prep (one-time): transpose + bf16 hi/lo split ----------
__global__ __launch_bounds__(256) void k_wprep(const float* __restrict__ W1, const float* __restrict__ W2,
                                               const float* __restrict__ nW, const float* __restrict__ gW,
                                               const float* __restrict__ nbp, const float* __restrict__ gb,
                                               unsigned short* __restrict__ w1h, unsigned short* __restrict__ w1l,
                                               unsigned short* __restrict__ w2h, unsigned short* __restrict__ w2l,
                                               unsigned short* __restrict__ whh, unsigned short* __restrict__ whl,
                                               float* __restrict__ bc) {
    int i = blockIdx.x * 256 + threadIdx.x;
    if (i < 48 * 64) {
        int j = i >> 6, k = i & 63;
        float v = 0.f;
        if (j < ON) v = nW[k * ON + j];
        else if (j < 33) v = gW[k * OC + (j - ON)];
        unsigned short hi = f2b(v);
        whh[i] = hi;
        whl[i] = f2b(v - b2f(hi));
    }
    if (i < 48) bc[i] = (i < ON) ? nbp[i] : ((i < 33) ? gb[i - ON] : 0.f);
    if (i >= NL * H2 * HH) return;
    int l = i / (H2 * HH), r = i % (H2 * HH);
    {
        int c = r / HH, k = r % HH;
        float v = W1[(size_t)l * HH * H2 + (size_t)k * H2 + c];
        unsigned short hi = f2b(v);
        w1h[i] = hi;
        w1l[i] = f2b(v - b2f(hi));
    }
    {
        int c = r / H2, k = r % H2;
        float v = W2[(size_t)l * H2 * HH + (size_t)k * HH + c];
        unsigned short hi = f2b(v);
        w2h[i] = hi;
        w2l[i] = f2b(v - b2f(hi));
    }
}

// ---------- node encoder: h = x @ W + b  ([N,32]@[32,64]), also bf16 shadow ----------
__global__ __launch_bounds__(256) void k_encoder(const float* __restrict__ x, const float* __restrict__ W,
                                                 const float* __restrict__ b, float* __restrict__ h,
                                                 unsigned short* __restrict__ hbf) {
    __shared__ float Ws[INC * HH];
    __shared__ float bs[HH];
    int tid = threadIdx.x;
    for (int i = tid; i < INC * HH; i += 256) Ws[i] = W[i];
    if (tid < HH) bs[tid] = b[tid];
    __syncthreads();
    int wid = tid >> 6, lane = tid & 63;
    int n = blockIdx.x * 4 + wid;
    if (n >= NN) return;
    float v = (lane < INC) ? x[(size_t)n * INC + lane] : 0.f;
    float acc = bs[lane];
    #pragma unroll
    for (int k = 0; k < INC; ++k)
        acc += __shfl(v, k) * Ws[k * HH + lane];
    h[(size_t)n * HH + lane] = acc;
    hbf[(size_t)n * HH + lane] = f2b(acc);
}

// ---------- per-dst softmax aggregation: HALF-WAVE per node ----------
__global__ __launch_bounds__(256) void k_agg(const float* __restrict__ y,
                                             const unsigned short* __restrict__ ybf,
                                             const int2* __restrict__ meta,
                                             const int* __restrict__ ssrc,
                                             const float* __restrict__ tp,
                                             unsigned short* __restrict__ agh,
                                             unsigned short* __restrict__ agl) {
    int tid = threadIdx.x;
    int w = tid >> 6, lane = tid & 63;
    int half = lane >> 5;          // 0 -> node A, 1 -> node B
    int l = lane & 31;             // index within half
    int col = l;                   // channel-pair (channels 2col, 2col+1)
    int n = blockIdx.x * 8 + w * 2 + half;
    bool valid = n < NN;
    float tval = *tp;
    int2 m = valid ? meta[n] : make_int2(0, 0);
    int start = m.x, deg = m.y;

    int dA = __shfl(deg, 0), dB = __shfl(deg, 32);
    int dmax = max(dA, dB);

    float Sa0 = 0.f, Sm0 = 0.f, Sa1 = 0.f, Sm1 = 0.f;
    for (int win = 0; win < dmax; win += 64) {
        int rem = dmax - win;                       // uniform
        int wcnt = min(64, rem);                    // uniform inner bound
        int idxLo = (win + l < deg) ? ssrc[start + win + l] : 0;
        int idxHi = (win + 32 + l < deg) ? ssrc[start + win + 32 + l] : 0;
        for (int e0 = 0; e0 < wcnt; e0 += 8) {
            float c0[8], c1[8];
            int ev[8];
            #pragma unroll
            for (int i = 0; i < 8; ++i) {
                int e = e0 + i;                     // uniform
                ev[i] = win + e;
                int sel = (e < 32) ? idxLo : idxHi;
                int s = __shfl(sel, (lane & 32) | (e & 31));
                unsigned v = *(const unsigned*)(ybf + (size_t)s * HH + col * 2);
                c0[i] = b2f((unsigned short)(v & 0xffffu));
                c1[i] = b2f((unsigned short)(v >> 16));
            }
            #pragma unroll
            for (int i = 0; i < 8; ++i) {
                bool ok = ev[i] < deg;              // uniform per half
                float m0 = fmaxf(c0[i], 0.f) + MEPS;
                float m1 = fmaxf(c1[i], 0.f) + MEPS;
                float a0 = ok ? __expf(tval * m0) : 0.f;
                float a1 = ok ? __expf(tval * m1) : 0.f;
                Sa0 += a0; Sm0 += m0 * a0;
                Sa1 += a1; Sm1 += m1 * a1;
            }
        }
    }
    if (!valid) return;
    float agg0 = Sm0 / fmaxf(Sa0, MEPS);            // deg==0 -> 0
    float agg1 = Sm1 / fmaxf(Sa1, MEPS);
    float2 yv = *(const float2*)(y + (size_t)n * HH + col * 2);
    float av0 = agg0 + yv.x;
    float av1 = agg1 + yv.y;
    unsigned short h0 = f2b(av0), h1 = f2b(av1);
    ushort2 ph = {h0, h1};
    ushort2 pl = {f2b(av0 - b2f(h0)), f2b(av1 - b2f(h1))};
    *(ushort2*)(agh + (size_t)n * HH + col * 2) = ph;
    *(ushort2*)(agl + (size_t)n * HH + col * 2) = pl;
}

// ---------- MFMA fused MLP with LDS-staged weights, 512-thread / 128-node blocks ----------
// Round-10 lever: double block -> half the blocks (391) -> weight staging traffic and
// barrier count halve (50->25MB), 8 waves/block cover staging latency. LDS 140KB/CU at
// 2 blocks; __launch_bounds__(512,4) caps VGPR at 128 so 2 blocks/CU hold.
// W1 hi/lo in ONE contiguous array so the Ut alias (8 waves x 4352B = 34816 <= 36864B)
// is guaranteed by construction.
__global__ __launch_bounds__(512, 4) void k_mlp(
    const unsigned short* __restrict__ agh, const unsigned short* __restrict__ agl,
    const unsigned short* __restrict__ w1h, const unsigned short* __restrict__ w1l,
    const float* __restrict__ b1,
    const float* __restrict__ mlg, const float* __restrict__ mlb,
    const unsigned short* __restrict__ w2h, const unsigned short* __restrict__ w2l,
    const float* __restrict__ b2,
    const float* __restrict__ hres, float* __restrict__ hout,
    const float* __restrict__ lng1, const float* __restrict__ lnb1,
    float* __restrict__ y, unsigned short* __restrict__ ybf)
{
    __shared__ __align__(16) unsigned short W1S[2 * 128 * 72];  // hi @0, lo @9216; Ut aliases later
    __shared__ __align__(16) unsigned short W2hS[64 * 136];     // 17408B
    __shared__ __align__(16) unsigned short W2lS[64 * 136];
    int tid = threadIdx.x;
    int w = tid >> 6, lane = tid & 63;
    int nl = lane & 15, g = lane >> 4;
    int node = blockIdx.x * 128 + w * 16 + nl;
    bool valid = node < NN;

    // ---- issue ag loads FIRST (HBM latency hides under weight staging)
    bf16x8 bAh[2], bAl[2];
    {
        bf16x8 z = {0, 0, 0, 0, 0, 0, 0, 0};
        if (valid) {
            const unsigned short* rp = agh + (size_t)node * HH + g * 8;
            bAh[0] = *(const bf16x8*)rp;
            bAh[1] = *(const bf16x8*)(rp + 32);
            const unsigned short* rq = agl + (size_t)node * HH + g * 8;
            bAl[0] = *(const bf16x8*)rq;
            bAl[1] = *(const bf16x8*)(rq + 32);
        } else {
            bAh[0] = z; bAh[1] = z; bAl[0] = z; bAl[1] = z;
        }
    }

    // ---- cooperative weight staging: 8 coalesced 16B loads/thread (512 threads)
    #pragma unroll
    for (int it = 0; it < 2; ++it) {                 // W1: 1024 hi + 1024 lo chunks
        int c = tid + it * 512;
        int row = c >> 3, col = (c & 7) << 3;
        float4 vh = *(const float4*)(w1h + c * 8);
        float4 vl = *(const float4*)(w1l + c * 8);
        *(float4*)&W1S[row * 72 + col] = vh;
        *(float4*)&W1S[9216 + row * 72 + col] = vl;
    }
    #pragma unroll
    for (int it = 0; it < 2; ++it) {                 // W2: 1024 hi + 1024 lo chunks
        int c = tid + it * 512;
        int row = c >> 4, col = (c & 15) << 3;
        float4 vh = *(const float4*)(w2h + c * 8);
        float4 vl = *(const float4*)(w2l + c * 8);
        *(float4*)&W2hS[row * 136 + col] = vh;
        *(float4*)&W2lS[row * 136 + col] = vl;
    }
    __syncthreads();

    // ---- gemmA: U^T tiles (8 x 16 ucols), K=64. 3 MFMA per (t,kc), frags from LDS
    f32x4 accU[8];
    #pragma unroll
    for (int t = 0; t < 8; ++t) {
        int uc = t * 16 + g * 4;
        float4 bb = *(const float4*)(b1 + uc);
        f32x4 a = {bb.x, bb.y, bb.z, bb.w};
        #pragma unroll
        for (int kc = 0; kc < 2; ++kc) {
            int wo = (t * 16 + nl) * 72 + kc * 32 + g * 8;
            bf16x8 ah = *(const bf16x8*)&W1S[wo];
            bf16x8 al = *(const bf16x8*)&W1S[9216 + wo];
            a = __builtin_amdgcn_mfma_f32_16x16x32_bf16(ah, bAh[kc], a, 0, 0, 0);
            a = __builtin_amdgcn_mfma_f32_16x16x32_bf16(al, bAh[kc], a, 0, 0, 0);
            a = __builtin_amdgcn_mfma_f32_16x16x32_bf16(ah, bAl[kc], a, 0, 0, 0);
        }
        accU[t] = a;
    }

    // ---- LN(128): node = lane&15 -> in-lane + 2 shfl_xor
    float s = 0.f, sq = 0.f;
    #pragma unroll
    for (int t = 0; t < 8; ++t) {
        #pragma unroll
        for (int j = 0; j < 4; ++j) { float v = accU[t][j]; s += v; sq += v * v; }
    }
    s += __shfl_xor(s, 16); sq += __shfl_xor(sq, 16);
    s += __shfl_xor(s, 32); sq += __shfl_xor(sq, 32);
    float mu = s * (1.f / 128.f);
    float var = sq * (1.f / 128.f) - mu * mu;
    float rs = rsqrtf(fmaxf(var, 0.f) + LNE);

    __syncthreads();   // all waves done reading W1 LDS -> Ut may overwrite it
    unsigned short* myUt = W1S + w * (16 * 136);    // 8 waves x 4352B = 34816 <= 36864B

    // normalize + relu + pack bf16 -> myUt[node][ucol]
    #pragma unroll
    for (int t = 0; t < 8; ++t) {
        int uc = t * 16 + g * 4;
        float4 gg = *(const float4*)(mlg + uc);
        float4 bb = *(const float4*)(mlb + uc);
        ushort4 pk;
        pk.x = f2b(fmaxf((accU[t][0] - mu) * rs * gg.x + bb.x, 0.f));
        pk.y = f2b(fmaxf((accU[t][1] - mu) * rs * gg.y + bb.y, 0.f));
        pk.z = f2b(fmaxf((accU[t][2] - mu) * rs * gg.z + bb.z, 0.f));
        pk.w = f2b(fmaxf((accU[t][3] - mu) * rs * gg.w + bb.w, 0.f));
        *(ushort4*)(&myUt[nl * 136 + uc]) = pk;
    }
    // per-wave slice: only our own wave's writes must land before our reads
    asm volatile("s_waitcnt lgkmcnt(0)" ::: "memory");

    // B-frags for gemmB: P^T
    bf16x8 bB[4];
    #pragma unroll
    for (int kc = 0; kc < 4; ++kc)
        bB[kc] = *(const bf16x8*)(&myUt[nl * 136 + kc * 32 + g * 8]);

    // gemmB: O^T tiles (4 x 16 ocols), K=128. 2 MFMA per (ot,kc), frags from LDS
    f32x4 accO[4];
    #pragma unroll
    for (int ot = 0; ot < 4; ++ot) {
        int oc = ot * 16 + g * 4;
        float4 bb = *(const float4*)(b2 + oc);
        f32x4 a = {bb.x, bb.y, bb.z, bb.w};
        #pragma unroll
        for (int kc = 0; kc < 4; ++kc) {
            int wo = (ot * 16 + nl) * 136 + kc * 32 + g * 8;
            bf16x8 ah = *(const bf16x8*)&W2hS[wo];
            bf16x8 al = *(const bf16x8*)&W2lS[wo];
            a = __builtin_amdgcn_mfma_f32_16x16x32_bf16(ah, bB[kc], a, 0, 0, 0);
            a = __builtin_amdgcn_mfma_f32_16x16x32_bf16(al, bB[kc], a, 0, 0, 0);
        }
        accO[ot] = a;
    }

    // epilogue: +residual, write h
    float4 oo[4];
    #pragma unroll
    for (int ot = 0; ot < 4; ++ot) {
        int oc = ot * 16 + g * 4;
        float4 o;
        o.x = accO[ot][0]; o.y = accO[ot][1]; o.z = accO[ot][2]; o.w = accO[ot][3];
        if (valid) {
            if (hres) {
                float4 hr = *(const float4*)(hres + (size_t)node * HH + oc);
                o.x += hr.x; o.y += hr.y; o.z += hr.z; o.w += hr.w;
            }
            *(float4*)(hout + (size_t)node * HH + oc) = o;
        }
        oo[ot] = o;
    }
    if (!lng1) return;   // last layer: k_outg does the final LN (uniform exit)

    // next-layer LN(64)+ReLU, all in registers
    float s2 = 0.f, sq2 = 0.f;
    #pragma unroll
    for (int ot = 0; ot < 4; ++ot) {
        s2 += oo[ot].x + oo[ot].y + oo[ot].z + oo[ot].w;
        sq2 += oo[ot].x * oo[ot].x + oo[ot].y * oo[ot].y
             + oo[ot].z * oo[ot].z + oo[ot].w * oo[ot].w;
    }
    s2 += __shfl_xor(s2, 16); sq2 += __shfl_xor(sq2, 16);
    s2 += __shfl_xor(s2, 32); sq2 += __shfl_xor(sq2, 32);
    float mu2 = s2 * (1.f / 64.f);
    float var2 = sq2 * (1.f / 64.f) - mu2 * mu2;
    float rs2 = rsqrtf(fmaxf(var2, 0.f) + LNE);
    #pragma unroll
    for (int ot = 0; ot < 4; ++ot) {
        int oc = ot * 16 + g * 4;
        float4 gg = *(const float4*)(lng1 + oc);
        float4 bb = *(const float4*)(lnb1 + oc);
        float4 v;
        v.x = fmaxf((oo[ot].x - mu2) * rs2 * gg.x + bb.x, 0.f);
        v.y = fmaxf((oo[ot].y - mu2) * rs2 * gg.y + bb.y, 0.f);
        v.z = fmaxf((oo[ot].z - mu2) * rs2 * gg.z + bb.z, 0.f);
        v.w = fmaxf((oo[ot].w - mu2) * rs2 * gg.w + bb.w, 0.f);
        if (valid) {
            *(float4*)(y + (size_t)node * HH + oc) = v;
            ushort4 p;
            p.x = f2b(v.x); p.y = f2b(v.y); p.z = f2b(v.z); p.w = f2b(v.w);
            *(ushort4*)(ybf + (size_t)node * HH + oc) = p;
        }
    }
}

// ---------- MFMA final LN + both heads; g-head via dense per-block max (NO atomics) ----------
__global__ __launch_bounds__(256) void k_outg(const float* __restrict__ h,
                                              const float* __restrict__ lng, const float* __restrict__ lnb,
                                              const unsigned short* __restrict__ whh,
                                              const unsigned short* __restrict__ whl,
                                              const float* __restrict__ bc,
                                              float* __restrict__ dout, float* __restrict__ gmax) {
    __shared__ float smax[4][16];
    int tid = threadIdx.x;
    int w = tid >> 6, lane = tid & 63;
    int nl = lane & 15, g = lane >> 4;
    int node = blockIdx.x * 64 + w * 16 + nl;
    bool valid = node < NN;

    // load h chunks: k = kc*32 + g*8 + e
    float hv[16];
    if (valid) {
        const float* hp = h + (size_t)node * HH;
        float4 a0 = *(const float4*)(hp + g * 8);
        float4 a1 = *(const float4*)(hp + g * 8 + 4);
        float4 a2 = *(const float4*)(hp + 32 + g * 8);
        float4 a3 = *(const float4*)(hp + 32 + g * 8 + 4);
        hv[0] = a0.x; hv[1] = a0.y; hv[2] = a0.z; hv[3] = a0.w;
        hv[4] = a1.x; hv[5] = a1.y; hv[6] = a1.z; hv[7] = a1.w;
        hv[8] = a2.x; hv[9] = a2.y; hv[10] = a2.z; hv[11] = a2.w;
        hv[12] = a3.x; hv[13] = a3.y; hv[14] = a3.z; hv[15] = a3.w;
    } else {
        #pragma unroll
        for (int i = 0; i < 16; ++i) hv[i] = 0.f;
    }

    // LN(64) stats
    float s = 0.f, sq = 0.f;
    #pragma unroll
    for (int i = 0; i < 16; ++i) { s += hv[i]; sq += hv[i] * hv[i]; }
    s += __shfl_xor(s, 16); sq += __shfl_xor(sq, 16);
    s += __shfl_xor(s, 32); sq += __shfl_xor(sq, 32);
    float mu = s * (1.f / 64.f);
    float var = sq * (1.f / 64.f) - mu * mu;
    float rs = rsqrtf(fmaxf(var, 0.f) + LNE);

    // normalize + relu, pack bf16 hi/lo B-frags
    union { bf16x8 v; unsigned short u[8]; } Bh[2], Bl[2];
    #pragma unroll
    for (int kc = 0; kc < 2; ++kc) {
        int cb = kc * 32 + g * 8;
        float4 g0 = *(const float4*)(lng + cb);
        float4 g1 = *(const float4*)(lng + cb + 4);
        float4 b0 = *(const float4*)(lnb + cb);
        float4 b1v = *(const float4*)(lnb + cb + 4);
        float gv[8] = {g0.x, g0.y, g0.z, g0.w, g1.x, g1.y, g1.z, g1.w};
        float bv[8] = {b0.x, b0.y, b0.z, b0.w, b1v.x, b1v.y, b1v.z, b1v.w};
        #pragma unroll
        for (int e = 0; e < 8; ++e) {
            float v = fmaxf((hv[kc * 8 + e] - mu) * rs * gv[e] + bv[e], 0.f);
            unsigned short hi = f2b(v);
            Bh[kc].u[e] = hi;
            Bl[kc].u[e] = f2b(v - b2f(hi));
        }
    }

    // heads: 3 output tiles (j = t*16 + g*4 + reg), K=64, 3 MFMA per (t,kc)
    f32x4 acc[3];
    #pragma unroll
    for (int t = 0; t < 3; ++t) {
        int j0 = t * 16 + g * 4;
        float4 bb = *(const float4*)(bc + j0);
        f32x4 a = {bb.x, bb.y, bb.z, bb.w};
        #pragma unroll
        for (int kc = 0; kc < 2; ++kc) {
            size_t wo = (size_t)(t * 16 + nl) * 64 + kc * 32 + g * 8;
            bf16x8 ah = *(const bf16x8*)(whh + wo);
            bf16x8 al = *(const bf16x8*)(whl + wo);
            a = __builtin_amdgcn_mfma_f32_16x16x32_bf16(ah, Bh[kc].v, a, 0, 0, 0);
            a = __builtin_amdgcn_mfma_f32_16x16x32_bf16(al, Bh[kc].v, a, 0, 0, 0);
            a = __builtin_amdgcn_mfma_f32_16x16x32_bf16(ah, Bl[kc].v, a, 0, 0, 0);
        }
        acc[t] = a;
    }

    // n-head direct stores; g-head butterfly-max over node-lanes -> LDS -> block max
    #pragma unroll
    for (int t = 0; t < 3; ++t) {
        #pragma unroll
        for (int reg = 0; reg < 4; ++reg) {
            int j = t * 16 + g * 4 + reg;   // uniform within a g-group
            float val = acc[t][reg];
            if (j < ON) {
                if (valid) dout[OC + (size_t)node * ON + j] = val;
            } else if (j < 33) {
                float gv = valid ? val : -INFINITY;
                #pragma unroll
                for (int m = 1; m < 16; m <<= 1) gv = fmaxf(gv, __shfl_xor(gv, m));
                if (nl == 0) smax[w][j - ON] = gv;
            }
        }
    }
    __syncthreads();
    if (tid < 16) {
        float m = fmaxf(fmaxf(smax[0][tid], smax[1][tid]),
                        fmaxf(smax[2][tid], smax[3][tid]));
        gmax[(size_t)blockIdx.x * 16 + tid] = m;
    }
}

// 1-wave final reduce: gmax[NOB][16] -> dout[0..15]
__global__ void k_gdec(const float* __restrict__ gmax, float* __restrict__ dout) {
    int lane = threadIdx.x & 63;
    int ch = lane & 15, grp = lane >> 4;   // 4 groups stride over blocks
    float m = -INFINITY;
    for (int b = grp; b < NOB; b += 4) m = fmaxf(m, gmax[(size_t)b * 16 + ch]);
    m = fmaxf(m, __shfl_xor(m, 16));
    m = fmaxf(m, __shfl_xor(m, 32));
    if (lane < 16) dout[ch] = m;
}

// ---------- launch ----------
extern "C" void kernel_launch(void* const* d_in, const int* in_sizes, int n_in,
                              void* d_out, int out_size, void* d_ws, size_t ws_size,
                              hipStream_t stream) {
    const float* x     = (const float*)d_in[0];
    const float* nodeW = (const float*)d_in[1];
    const float* nodeB = (const float*)d_in[2];
    const float* W1    = (const float*)d_in[3];
    const float* b1    = (const float*)d_in[4];
    const float* mlg   = (const float*)d_in[5];
    const float* mlb   = (const float*)d_in[6];
    const float* W2    = (const float*)d_in[7];
    const float* b2    = (const float*)d_in[8];
    const float* tt    = (const float*)d_in[9];
    const float* lng   = (const float*)d_in[10];
    const float* lnb   = (const float*)d_in[11];
    const int*   ei    = (const int*)d_in[12];
    const float* gW    = (const float*)d_in[13];
    const float* gb    = (const float*)d_in[14];
    const float* nW    = (const float*)d_in[15];
    const float* nbp   = (const float*)d_in[16];
    float* out = (float*)d_out;

    char* ws = (char*)d_ws;
    size_t off = 0;
    auto alloc = [&](size_t bytes) -> void* {
        void* p = ws + off;
        off = (off + bytes + 255) & ~(size_t)255;
        return p;
    };
    int* counts    = (int*)alloc((size_t)NN * 4);
    size_t zero_end = off;
    float* gmax = (float*)alloc((size_t)NOB * 16 * 4);
    int* bsums = (int*)alloc(1024);
    int* rowst = (int*)alloc((size_t)NN * 4);
    int2* meta = (int2*)alloc((size_t)NN * 8);
    int* ssrc  = (int*)alloc((size_t)NE * 4);
    float* h   = (float*)alloc((size_t)NN * HH * 4);
    float* y   = (float*)alloc((size_t)NN * HH * 4);
    unsigned short* agh = (unsigned short*)alloc((size_t)NN * HH * 2);
    unsigned short* agl = (unsigned short*)alloc((size_t)NN * HH * 2);
    unsigned short* ybf = (unsigned short*)alloc((size_t)NN * HH * 2);
    unsigned short* w1h = (unsigned short*)alloc((size_t)NL * H2 * HH * 2);
    unsigned short* w1l = (unsigned short*)alloc((size_t)NL * H2 * HH * 2);
    unsigned short* w2h = (unsigned short*)alloc((size_t)NL * H2 * HH * 2);
    unsigned short* w2l = (unsigned short*)alloc((size_t)NL * H2 * HH * 2);
    unsigned short* whh = (unsigned short*)alloc((size_t)48 * 64 * 2);
    unsigned short* whl = (unsigned short*)alloc((size_t)48 * 64 * 2);
    float* bc = (float*)alloc(48 * 4);
    int* rank = (int*)agh;   // alias: rank only lives during CSR build (3.2MB <= 6.4MB)

    const int* esrc = ei;
    const int* edst = ei + NE;

    hipMemsetAsync(d_ws, 0, zero_end, stream);

    k_wprep<<<(NL * H2 * HH + 255) / 256, 256, 0, stream>>>(W1, W2, nW, gW, nbp, gb,
                                                            w1h, w1l, w2h, w2l, whh, whl, bc);
    k_hist2<<<(NE + 255) / 256, 256, 0, stream>>>(edst, counts, rank);
    k_scan1<<<SCAN_BLOCKS, 256, 0, stream>>>(counts, rowst, bsums);
    k_scan2<<<1, 256, 0, stream>>>(bsums);
    k_scan3<<<SCAN_BLOCKS, 256, 0, stream>>>(counts, rowst, bsums, meta);
    k_scatter2<<<(NE + 255) / 256, 256, 0, stream>>>(esrc, edst, rank, rowst, ssrc);
    k_encoder<<<(NN + 3) / 4, 256, 0, stream>>>(x, nodeW, nodeB, h, ybf);

    for (int l = 0; l < NL; ++l) {
        const float* yin = (l == 0) ? h : y;
        k_agg<<<(NN + 7) / 8, 256, 0, stream>>>(yin, ybf, meta, ssrc, tt + l, agh, agl);
        const float* ln1g = (l < NL - 1) ? (lng + (size_t)(l + 1) * HH) : nullptr;
        const float* ln1b = (l < NL - 1) ? (lnb + (size_t)(l + 1) * HH) : nullptr;
        k_mlp<<<(NN + 127) / 128, 512, 0, stream>>>(agh, agl,
                                                    w1h + (size_t)l * H2 * HH, w1l + (size_t)l * H2 * HH,
                                                    b1 + (size_t)l * H2,
                                                    mlg + (size_t)l * H2, mlb + (size_t)l * H2,
                                                    w2h + (size_t)l * H2 * HH, w2l + (size_t)l * H2 * HH,
                                                    b2 + (size_t)l * HH,
                                                    (l == 0) ? (const float*)nullptr : h, h,
                                                    ln1g, ln1b, y, ybf);
    }
    k_outg<<<NOB, 256, 0, stream>>>(h, lng, lnb, whh, whl, bc, out, gmax);
    k_gdec<<<1, 64, 0, stream>>>(gmax, out);
}